// Round 1
// baseline (1045.799 us; speedup 1.0000x reference)
//
#include <hip/hip_runtime.h>
#include <cstdint>
#include <cstddef>

#define NNODE 8192
#define NEDGE 262144

// ---------------- utility kernels ----------------

__global__ void k_zero_int(int* p, int n) {
    int i = blockIdx.x * blockDim.x + threadIdx.x;
    if (i < n) p[i] = 0;
}

__global__ void k_count(const int* __restrict__ dst, int* __restrict__ cnt, int n) {
    int i = blockIdx.x * blockDim.x + threadIdx.x;
    if (i < n) atomicAdd(&cnt[dst[i]], 1);
}

// single block: exclusive scan of cnt[8192] -> row_start/cursor, dinv = rsqrt(deg+1)
__global__ __launch_bounds__(256) void k_scan(const int* __restrict__ cnt,
                                              int* __restrict__ row_start,
                                              int* __restrict__ cursor,
                                              float* __restrict__ dinv) {
    __shared__ int part[256];
    const int tid = threadIdx.x;
    const int PER = NNODE / 256;  // 32
    const int base = tid * PER;
    int loc[PER];
    int sum = 0;
#pragma unroll
    for (int i = 0; i < PER; ++i) { loc[i] = cnt[base + i]; sum += loc[i]; }
    part[tid] = sum;
    __syncthreads();
    if (tid == 0) {
        int r = 0;
        for (int i = 0; i < 256; ++i) { int t = part[i]; part[i] = r; r += t; }
    }
    __syncthreads();
    int run = part[tid];
#pragma unroll
    for (int i = 0; i < PER; ++i) {
        row_start[base + i] = run;
        cursor[base + i] = run;
        dinv[base + i] = rsqrtf((float)loc[i] + 1.0f);  // deg = in-degree + self loop
        run += loc[i];
    }
    if (tid == 255) row_start[NNODE] = run;
}

__global__ void k_fill_csr(const int* __restrict__ dst, int* __restrict__ cursor,
                           int* __restrict__ elist, int n) {
    int e = blockIdx.x * blockDim.x + threadIdx.x;
    if (e < n) {
        int pos = atomicAdd(&cursor[dst[e]], 1);
        elist[pos] = e;
    }
}

// ---------------- generic fused-concat GEMM ----------------
// C[M,N] = act( A1[M,K1] @ W[0:K1, :] + A2[M,K2] @ W[K1:K1+K2, :] + bias )
// BM=BN=64, BK=16, 256 threads (16x16), 4x4 microtile. All dims multiples of tile sizes.
__global__ __launch_bounds__(256) void k_gemm(
    const float* __restrict__ A1, int K1,
    const float* __restrict__ A2, int K2,
    const float* __restrict__ W, int N,
    const float* __restrict__ bias,
    float* __restrict__ C, int ldc, int relu) {
    __shared__ float sA[16][68];  // [k][m], +4 pad keeps float4 alignment & spreads banks
    __shared__ float sB[16][68];  // [k][n]
    const int tid = threadIdx.x;
    const int tx = tid & 15, ty = tid >> 4;
    const int bm = blockIdx.y * 64;
    const int bn = blockIdx.x * 64;
    const int arow = tid >> 2, ac4 = (tid & 3) * 4;
    const int brow = tid >> 4, bc4 = (tid & 15) * 4;
    float acc[4][4] = {};
    const int Ktot = K1 + K2;
    for (int k0 = 0; k0 < Ktot; k0 += 16) {
        const float* A;
        int lda, kk0;
        if (k0 < K1) { A = A1; lda = K1; kk0 = k0; }
        else         { A = A2; lda = K2; kk0 = k0 - K1; }
        float4 va = *(const float4*)(A + (size_t)(bm + arow) * lda + kk0 + ac4);
        float4 vb = *(const float4*)(W + (size_t)(k0 + brow) * N + bn + bc4);
        sA[ac4 + 0][arow] = va.x; sA[ac4 + 1][arow] = va.y;
        sA[ac4 + 2][arow] = va.z; sA[ac4 + 3][arow] = va.w;
        *(float4*)&sB[brow][bc4] = vb;
        __syncthreads();
#pragma unroll
        for (int kk = 0; kk < 16; ++kk) {
            float av[4], bv[4];
            *(float4*)av = *(const float4*)&sA[kk][ty * 4];
            *(float4*)bv = *(const float4*)&sB[kk][tx * 4];
#pragma unroll
            for (int i = 0; i < 4; ++i)
#pragma unroll
                for (int j = 0; j < 4; ++j) acc[i][j] += av[i] * bv[j];
        }
        __syncthreads();
    }
#pragma unroll
    for (int i = 0; i < 4; ++i) {
        const int row = bm + ty * 4 + i;
        float4 v;
        float* pv = (float*)&v;
#pragma unroll
        for (int j = 0; j < 4; ++j) {
            float x = acc[i][j];
            if (bias) x += bias[bn + tx * 4 + j];
            if (relu) x = fmaxf(x, 0.0f);
            pv[j] = x;
        }
        *(float4*)(C + (size_t)row * ldc + bn + tx * 4) = v;
    }
}

// ---------------- GCN aggregation (gather over CSR-by-dst) ----------------
// out[n,:] = sum_{e: dst=n} dinv[src]*dinv[n]*h[src,:] + dinv[n]^2*h[n,:] + bias
template <int CPT>  // channels per thread; D = 256*CPT
__global__ __launch_bounds__(256) void k_agg(
    const int* __restrict__ row_start, const int* __restrict__ elist,
    const int* __restrict__ srcArr, const float* __restrict__ dinv,
    const float* __restrict__ h, const float* __restrict__ bias,
    float* __restrict__ out) {
    const int D = 256 * CPT;
    const int n = blockIdx.x;
    const int c = threadIdx.x;
    const float di = dinv[n];
    float acc[CPT];
#pragma unroll
    for (int i = 0; i < CPT; ++i)
        acc[i] = di * di * h[(size_t)n * D + c + i * 256] + bias[c + i * 256];
    const int s0 = row_start[n], s1 = row_start[n + 1];
    for (int j = s0; j < s1; ++j) {
        int e = elist[j];
        int s = srcArr[e];
        float w = dinv[s] * di;
#pragma unroll
        for (int i = 0; i < CPT; ++i)
            acc[i] += w * h[(size_t)s * D + c + i * 256];
    }
#pragma unroll
    for (int i = 0; i < CPT; ++i) out[(size_t)n * D + c + i * 256] = acc[i];
}

// ---------------- out = sigmoid(Z @ Z^T), symmetric ----------------
// 128x128 tiles, 256 threads, 8x8 microtile, K=512. Upper-triangular blocks only;
// mirror tile written via register transpose (float4 chunks).
__global__ __launch_bounds__(256) void k_zzt(const float* __restrict__ Z,
                                             float* __restrict__ out) {
    const int bi = blockIdx.y, bj = blockIdx.x;
    if (bi > bj) return;
    __shared__ float sA[16][132];
    __shared__ float sB[16][132];
    const int tid = threadIdx.x;
    const int tx = tid & 15, ty = tid >> 4;
    float acc[8][8] = {};
    for (int k0 = 0; k0 < 512; k0 += 16) {
#pragma unroll
        for (int i = 0; i < 2; ++i) {
            int t = tid + i * 256;  // 0..511
            int row = t >> 2, c4 = (t & 3) * 4;
            float4 va = *(const float4*)(Z + (size_t)(bi * 128 + row) * 512 + k0 + c4);
            sA[c4 + 0][row] = va.x; sA[c4 + 1][row] = va.y;
            sA[c4 + 2][row] = va.z; sA[c4 + 3][row] = va.w;
            float4 vb = *(const float4*)(Z + (size_t)(bj * 128 + row) * 512 + k0 + c4);
            sB[c4 + 0][row] = vb.x; sB[c4 + 1][row] = vb.y;
            sB[c4 + 2][row] = vb.z; sB[c4 + 3][row] = vb.w;
        }
        __syncthreads();
#pragma unroll
        for (int kk = 0; kk < 16; ++kk) {
            float a[8], b[8];
            *(float4*)&a[0] = *(const float4*)&sA[kk][ty * 8];
            *(float4*)&a[4] = *(const float4*)&sA[kk][ty * 8 + 4];
            *(float4*)&b[0] = *(const float4*)&sB[kk][tx * 8];
            *(float4*)&b[4] = *(const float4*)&sB[kk][tx * 8 + 4];
#pragma unroll
            for (int i = 0; i < 8; ++i)
#pragma unroll
                for (int j = 0; j < 8; ++j) acc[i][j] += a[i] * b[j];
        }
        __syncthreads();
    }
#pragma unroll
    for (int i = 0; i < 8; ++i)
#pragma unroll
        for (int j = 0; j < 8; ++j) acc[i][j] = 1.0f / (1.0f + __expf(-acc[i][j]));
    // own tile
#pragma unroll
    for (int i = 0; i < 8; ++i) {
        size_t rbase = (size_t)(bi * 128 + ty * 8 + i) * 8192 + bj * 128 + tx * 8;
        *(float4*)(out + rbase)     = make_float4(acc[i][0], acc[i][1], acc[i][2], acc[i][3]);
        *(float4*)(out + rbase + 4) = make_float4(acc[i][4], acc[i][5], acc[i][6], acc[i][7]);
    }
    // mirror tile (register transpose)
    if (bi != bj) {
#pragma unroll
        for (int j = 0; j < 8; ++j) {
            size_t rbase = (size_t)(bj * 128 + tx * 8 + j) * 8192 + bi * 128 + ty * 8;
            *(float4*)(out + rbase)     = make_float4(acc[0][j], acc[1][j], acc[2][j], acc[3][j]);
            *(float4*)(out + rbase + 4) = make_float4(acc[4][j], acc[5][j], acc[6][j], acc[7][j]);
        }
    }
}

// ---------------- launch ----------------
extern "C" void kernel_launch(void* const* d_in, const int* in_sizes, int n_in,
                              void* d_out, int out_size, void* d_ws, size_t ws_size,
                              hipStream_t stream) {
    const float* x_self     = (const float*)d_in[0];
    const float* x_neighbor = (const float*)d_in[1];
    const int*   ei         = (const int*)d_in[2];
    const float* w_in_self  = (const float*)d_in[3];
    const float* b_in_self  = (const float*)d_in[4];
    const float* w_out_self = (const float*)d_in[5];
    const float* b_out_self = (const float*)d_in[6];
    const float* gw1        = (const float*)d_in[7];
    const float* gb1        = (const float*)d_in[8];
    const float* gw2        = (const float*)d_in[9];
    const float* gb2        = (const float*)d_in[10];
    const float* w_out      = (const float*)d_in[11];
    const float* b_out      = (const float*)d_in[12];
    float* out = (float*)d_out;

    char* ws = (char*)d_ws;
    const size_t MB = 1024 * 1024;
    int*   cnt       = (int*)(ws + 0);                    // 8192 ints
    int*   row_start = (int*)(ws + 32 * 1024);            // 8193 ints
    int*   cursor    = (int*)(ws + 68 * 1024);            // 8192 ints
    int*   elist     = (int*)(ws + 100 * 1024);           // 262144 ints (1 MB)
    float* dinv      = (float*)(ws + 100 * 1024 + MB);    // 8192 floats
    float* bufA = (float*)(ws + 2 * MB);   // 16 MB: h1, then h2, then l1
    float* bufB = (float*)(ws + 18 * MB);  // 16 MB: g1
    float* bufC = (float*)(ws + 34 * MB);  // 8 MB:  g2
    float* z    = (float*)(ws + 42 * MB);  // 16 MB: [l1b | x2]

    const int* srcA = ei;          // edge_index[0]
    const int* dstA = ei + NEDGE;  // edge_index[1]

    // CSR build (by dst) + degree norm
    k_zero_int<<<NNODE / 256, 256, 0, stream>>>(cnt, NNODE);
    k_count<<<NEDGE / 256, 256, 0, stream>>>(dstA, cnt, NEDGE);
    k_scan<<<1, 256, 0, stream>>>(cnt, row_start, cursor, dinv);
    k_fill_csr<<<NEDGE / 256, 256, 0, stream>>>(dstA, cursor, elist, NEDGE);

    // h1 = x_self @ gw1                       [8192,512]
    k_gemm<<<dim3(512 / 64, NNODE / 64), 256, 0, stream>>>(
        x_self, 512, nullptr, 0, gw1, 512, nullptr, bufA, 512, 0);
    // g1 = S @ h1 + gb1
    k_agg<2><<<NNODE, 256, 0, stream>>>(row_start, elist, srcA, dinv, bufA, gb1, bufB);
    // h2 = g1 @ gw2                           [8192,256]
    k_gemm<<<dim3(256 / 64, NNODE / 64), 256, 0, stream>>>(
        bufB, 512, nullptr, 0, gw2, 256, nullptr, bufA, 256, 0);
    // g2 = S @ h2 + gb2
    k_agg<1><<<NNODE, 256, 0, stream>>>(row_start, elist, srcA, dinv, bufA, gb2, bufC);
    // l1 = relu(x_self @ w_in_self + b_in_self)   (bufA reused; h2 already consumed)
    k_gemm<<<dim3(512 / 64, NNODE / 64), 256, 0, stream>>>(
        x_self, 512, nullptr, 0, w_in_self, 512, b_in_self, bufA, 512, 1);
    // z[:, :256] = [x_self | l1] @ w_out_self + b_out_self
    k_gemm<<<dim3(256 / 64, NNODE / 64), 256, 0, stream>>>(
        x_self, 512, bufA, 512, w_out_self, 256, b_out_self, z, 512, 0);
    // z[:, 256:] = [x_neighbor | g2] @ w_out + b_out
    k_gemm<<<dim3(256 / 64, NNODE / 64), 256, 0, stream>>>(
        x_neighbor, 512, bufC, 256, w_out, 256, b_out, z + 256, 512, 0);
    // out = sigmoid(z z^T)
    k_zzt<<<dim3(NNODE / 128, NNODE / 128), 256, 0, stream>>>(z, out);
}

// Round 2
// 684.212 us; speedup vs baseline: 1.5285x; 1.5285x over previous
//
#include <hip/hip_runtime.h>
#include <cstdint>
#include <cstddef>

#define NNODE 8192
#define NEDGE 262144

typedef __attribute__((ext_vector_type(8))) short bf16x8;
typedef __attribute__((ext_vector_type(4))) float f32x4;

// ---------------- utility kernels ----------------

__global__ void k_zero_int(int* p, int n) {
    int i = blockIdx.x * blockDim.x + threadIdx.x;
    if (i < n) p[i] = 0;
}

__global__ void k_count(const int* __restrict__ dst, int* __restrict__ cnt, int n) {
    int i = blockIdx.x * blockDim.x + threadIdx.x;
    if (i < n) atomicAdd(&cnt[dst[i]], 1);
}

// single block: exclusive scan of cnt[8192] -> row_start/cursor, dinv = rsqrt(deg+1)
__global__ __launch_bounds__(256) void k_scan(const int* __restrict__ cnt,
                                              int* __restrict__ row_start,
                                              int* __restrict__ cursor,
                                              float* __restrict__ dinv) {
    __shared__ int part[256];
    const int tid = threadIdx.x;
    const int PER = NNODE / 256;  // 32
    const int base = tid * PER;
    int loc[PER];
    int sum = 0;
#pragma unroll
    for (int i = 0; i < PER; ++i) { loc[i] = cnt[base + i]; sum += loc[i]; }
    part[tid] = sum;
    __syncthreads();
    if (tid == 0) {
        int r = 0;
        for (int i = 0; i < 256; ++i) { int t = part[i]; part[i] = r; r += t; }
    }
    __syncthreads();
    int run = part[tid];
#pragma unroll
    for (int i = 0; i < PER; ++i) {
        row_start[base + i] = run;
        cursor[base + i] = run;
        dinv[base + i] = rsqrtf((float)loc[i] + 1.0f);  // deg = in-degree + self loop
        run += loc[i];
    }
    if (tid == 255) row_start[NNODE] = run;
}

__global__ void k_fill_csr(const int* __restrict__ dst, int* __restrict__ cursor,
                           int* __restrict__ elist, int n) {
    int e = blockIdx.x * blockDim.x + threadIdx.x;
    if (e < n) {
        int pos = atomicAdd(&cursor[dst[e]], 1);
        elist[pos] = e;
    }
}

// ---------------- generic fused-concat GEMM (fp32 VALU) ----------------
__global__ __launch_bounds__(256) void k_gemm(
    const float* __restrict__ A1, int K1,
    const float* __restrict__ A2, int K2,
    const float* __restrict__ W, int N,
    const float* __restrict__ bias,
    float* __restrict__ C, int ldc, int relu) {
    __shared__ float sA[16][68];
    __shared__ float sB[16][68];
    const int tid = threadIdx.x;
    const int tx = tid & 15, ty = tid >> 4;
    const int bm = blockIdx.y * 64;
    const int bn = blockIdx.x * 64;
    const int arow = tid >> 2, ac4 = (tid & 3) * 4;
    const int brow = tid >> 4, bc4 = (tid & 15) * 4;
    float acc[4][4] = {};
    const int Ktot = K1 + K2;
    for (int k0 = 0; k0 < Ktot; k0 += 16) {
        const float* A;
        int lda, kk0;
        if (k0 < K1) { A = A1; lda = K1; kk0 = k0; }
        else         { A = A2; lda = K2; kk0 = k0 - K1; }
        float4 va = *(const float4*)(A + (size_t)(bm + arow) * lda + kk0 + ac4);
        float4 vb = *(const float4*)(W + (size_t)(k0 + brow) * N + bn + bc4);
        sA[ac4 + 0][arow] = va.x; sA[ac4 + 1][arow] = va.y;
        sA[ac4 + 2][arow] = va.z; sA[ac4 + 3][arow] = va.w;
        *(float4*)&sB[brow][bc4] = vb;
        __syncthreads();
#pragma unroll
        for (int kk = 0; kk < 16; ++kk) {
            float av[4], bv[4];
            *(float4*)av = *(const float4*)&sA[kk][ty * 4];
            *(float4*)bv = *(const float4*)&sB[kk][tx * 4];
#pragma unroll
            for (int i = 0; i < 4; ++i)
#pragma unroll
                for (int j = 0; j < 4; ++j) acc[i][j] += av[i] * bv[j];
        }
        __syncthreads();
    }
#pragma unroll
    for (int i = 0; i < 4; ++i) {
        const int row = bm + ty * 4 + i;
        float4 v;
        float* pv = (float*)&v;
#pragma unroll
        for (int j = 0; j < 4; ++j) {
            float x = acc[i][j];
            if (bias) x += bias[bn + tx * 4 + j];
            if (relu) x = fmaxf(x, 0.0f);
            pv[j] = x;
        }
        *(float4*)(C + (size_t)row * ldc + bn + tx * 4) = v;
    }
}

// ---------------- GCN aggregation (gather over CSR-by-dst) ----------------
template <int CPT>
__global__ __launch_bounds__(256) void k_agg(
    const int* __restrict__ row_start, const int* __restrict__ elist,
    const int* __restrict__ srcArr, const float* __restrict__ dinv,
    const float* __restrict__ h, const float* __restrict__ bias,
    float* __restrict__ out) {
    const int D = 256 * CPT;
    const int n = blockIdx.x;
    const int c = threadIdx.x;
    const float di = dinv[n];
    float acc[CPT];
#pragma unroll
    for (int i = 0; i < CPT; ++i)
        acc[i] = di * di * h[(size_t)n * D + c + i * 256] + bias[c + i * 256];
    const int s0 = row_start[n], s1 = row_start[n + 1];
    for (int j = s0; j < s1; ++j) {
        int e = elist[j];
        int s = srcArr[e];
        float w = dinv[s] * di;
#pragma unroll
        for (int i = 0; i < CPT; ++i)
            acc[i] += w * h[(size_t)s * D + c + i * 256];
    }
#pragma unroll
    for (int i = 0; i < CPT; ++i) out[(size_t)n * D + c + i * 256] = acc[i];
}

// ---------------- split z (fp32) -> z_hi + z_lo (bf16, RN) ----------------
__device__ __forceinline__ unsigned short f2bf_rn(float x) {
    unsigned u = __float_as_uint(x);
    u = (u + 0x7FFFu + ((u >> 16) & 1u)) >> 16;
    return (unsigned short)u;
}

__global__ __launch_bounds__(256) void k_split(const float* __restrict__ z,
                                               unsigned short* __restrict__ hi,
                                               unsigned short* __restrict__ lo) {
    const int i = blockIdx.x * blockDim.x + threadIdx.x;  // 4 floats per thread
    float4 v = ((const float4*)z)[i];
    float x[4] = {v.x, v.y, v.z, v.w};
    unsigned short h[4], l[4];
#pragma unroll
    for (int j = 0; j < 4; ++j) {
        h[j] = f2bf_rn(x[j]);
        float hf = __uint_as_float(((unsigned)h[j]) << 16);
        l[j] = f2bf_rn(x[j] - hf);
    }
    ((ushort4*)hi)[i] = make_ushort4(h[0], h[1], h[2], h[3]);
    ((ushort4*)lo)[i] = make_ushort4(l[0], l[1], l[2], l[3]);
}

// ---------------- out = sigmoid(Z Z^T) via split-bf16 MFMA ----------------
// Lower-triangular block grid (2080 blocks), 128x128 tile, 4 waves, 16x16x32 bf16 MFMA.
// score = hi*hi^T + hi*lo^T + lo*hi^T  (lo*lo^T dropped, ~1e-3 pre-sigmoid).
// LDS: 4 tiles of 128x32 bf16 (A_hi, A_lo, B_hi, B_lo) = 32 KB, single-buffered.
// Staging: global_load_lds w=16, source pre-swizzled so that LDS slot (r,s)
// holds k-chunk s^(r&3); fragment reads apply the same XOR (rule #21).
__global__ __launch_bounds__(256) void k_zzt_mfma(const unsigned short* __restrict__ zhi,
                                                  const unsigned short* __restrict__ zlo,
                                                  float* __restrict__ out) {
    __shared__ __align__(16) char smem[32768];
    const int tid = threadIdx.x;
    const int lane = tid & 63;
    const int w = tid >> 6;
    const int wr = w >> 1, wc = w & 1;

    // decode lower-triangular (bi >= bj) from linear block id
    const int t = blockIdx.x;
    int bi = (int)((sqrtf(8.0f * (float)t + 1.0f) - 1.0f) * 0.5f);
    while ((bi + 1) * (bi + 2) / 2 <= t) ++bi;
    while (bi * (bi + 1) / 2 > t) --bi;
    const int bj = t - bi * (bi + 1) / 2;

    const char* srcs[4];
    srcs[0] = (const char*)zhi + (size_t)(bi * 128) * 1024;
    srcs[1] = (const char*)zlo + (size_t)(bi * 128) * 1024;
    srcs[2] = (const char*)zhi + (size_t)(bj * 128) * 1024;
    srcs[3] = (const char*)zlo + (size_t)(bj * 128) * 1024;

    const int rloc = w * 16 + (lane >> 2);                    // staging row (instr i adds 64)
    const int swz_src = ((lane & 3) ^ ((lane >> 2) & 3)) * 16;  // pre-swizzled source slot
    const int sread = ((lane >> 4) ^ (lane & 3)) * 16;          // swizzled read slot

    f32x4 acc[4][4] = {};

    for (int k0 = 0; k0 < 512; k0 += 32) {
        const int kbyte = k0 * 2;
#pragma unroll
        for (int tile = 0; tile < 4; ++tile) {
#pragma unroll
            for (int i = 0; i < 2; ++i) {
                const char* gp = srcs[tile] + (size_t)(rloc + i * 64) * 1024 + kbyte + swz_src;
                char* lp = smem + tile * 8192 + i * 4096 + w * 1024;  // wave-uniform
                __builtin_amdgcn_global_load_lds(
                    (const __attribute__((address_space(1))) void*)gp,
                    (__attribute__((address_space(3))) void*)lp, 16, 0, 0);
            }
        }
        __syncthreads();  // drains vmcnt before any wave reads

        bf16x8 ah[4], al[4], bh[4], bl[4];
        const char* pa = smem + (wr * 64 + (lane & 15)) * 64 + sread;
        const char* pb = smem + 16384 + (wc * 64 + (lane & 15)) * 64 + sread;
#pragma unroll
        for (int m = 0; m < 4; ++m) {
            ah[m] = *(const bf16x8*)(pa + m * 1024);
            al[m] = *(const bf16x8*)(pa + 8192 + m * 1024);
        }
#pragma unroll
        for (int n = 0; n < 4; ++n) {
            bh[n] = *(const bf16x8*)(pb + n * 1024);
            bl[n] = *(const bf16x8*)(pb + 8192 + n * 1024);
        }
#pragma unroll
        for (int m = 0; m < 4; ++m)
#pragma unroll
            for (int n = 0; n < 4; ++n) {
                acc[m][n] = __builtin_amdgcn_mfma_f32_16x16x32_bf16(ah[m], bh[n], acc[m][n], 0, 0, 0);
                acc[m][n] = __builtin_amdgcn_mfma_f32_16x16x32_bf16(ah[m], bl[n], acc[m][n], 0, 0, 0);
                acc[m][n] = __builtin_amdgcn_mfma_f32_16x16x32_bf16(al[m], bh[n], acc[m][n], 0, 0, 0);
            }
        __syncthreads();  // before next K-step overwrites the buffer
    }

    // epilogue: sigmoid once, store tile + register-transposed mirror.
    // C/D layout (m89/m91): col = lane&15, row = (lane>>4)*4 + reg
    const int rj = (lane >> 4) * 4;
    const int cc = lane & 15;
#pragma unroll
    for (int m = 0; m < 4; ++m) {
#pragma unroll
        for (int n = 0; n < 4; ++n) {
            float s[4];
#pragma unroll
            for (int j = 0; j < 4; ++j)
                s[j] = 1.0f / (1.0f + __expf(-acc[m][n][j]));
            const int gr0 = bi * 128 + wr * 64 + m * 16 + rj;
            const int gc  = bj * 128 + wc * 64 + n * 16 + cc;
#pragma unroll
            for (int j = 0; j < 4; ++j)
                out[(size_t)(gr0 + j) * NNODE + gc] = s[j];
            if (bi != bj) {
                const int mr = bj * 128 + wc * 64 + n * 16 + cc;
                const int mc = bi * 128 + wr * 64 + m * 16 + rj;
                *(float4*)(out + (size_t)mr * NNODE + mc) = make_float4(s[0], s[1], s[2], s[3]);
            }
        }
    }
}

// ---------------- launch ----------------
extern "C" void kernel_launch(void* const* d_in, const int* in_sizes, int n_in,
                              void* d_out, int out_size, void* d_ws, size_t ws_size,
                              hipStream_t stream) {
    const float* x_self     = (const float*)d_in[0];
    const float* x_neighbor = (const float*)d_in[1];
    const int*   ei         = (const int*)d_in[2];
    const float* w_in_self  = (const float*)d_in[3];
    const float* b_in_self  = (const float*)d_in[4];
    const float* w_out_self = (const float*)d_in[5];
    const float* b_out_self = (const float*)d_in[6];
    const float* gw1        = (const float*)d_in[7];
    const float* gb1        = (const float*)d_in[8];
    const float* gw2        = (const float*)d_in[9];
    const float* gb2        = (const float*)d_in[10];
    const float* w_out      = (const float*)d_in[11];
    const float* b_out      = (const float*)d_in[12];
    float* out = (float*)d_out;

    char* ws = (char*)d_ws;
    const size_t MB = 1024 * 1024;
    int*   cnt       = (int*)(ws + 0);
    int*   row_start = (int*)(ws + 32 * 1024);
    int*   cursor    = (int*)(ws + 68 * 1024);
    int*   elist     = (int*)(ws + 100 * 1024);
    float* dinv      = (float*)(ws + 100 * 1024 + MB);
    float* bufA = (float*)(ws + 2 * MB);   // 16 MB: h1, then h2, then l1; later zhi/zlo
    float* bufB = (float*)(ws + 18 * MB);  // 16 MB: g1
    float* bufC = (float*)(ws + 34 * MB);  // 8 MB:  g2
    float* z    = (float*)(ws + 42 * MB);  // 16 MB: [l1b | x2]
    unsigned short* zhi = (unsigned short*)(ws + 2 * MB);   // 8 MB (bufA reuse)
    unsigned short* zlo = (unsigned short*)(ws + 10 * MB);  // 8 MB

    const int* srcA = ei;          // edge_index[0]
    const int* dstA = ei + NEDGE;  // edge_index[1]

    // CSR build (by dst) + degree norm
    k_zero_int<<<NNODE / 256, 256, 0, stream>>>(cnt, NNODE);
    k_count<<<NEDGE / 256, 256, 0, stream>>>(dstA, cnt, NEDGE);
    k_scan<<<1, 256, 0, stream>>>(cnt, row_start, cursor, dinv);
    k_fill_csr<<<NEDGE / 256, 256, 0, stream>>>(dstA, cursor, elist, NEDGE);

    // h1 = x_self @ gw1
    k_gemm<<<dim3(512 / 64, NNODE / 64), 256, 0, stream>>>(
        x_self, 512, nullptr, 0, gw1, 512, nullptr, bufA, 512, 0);
    // g1 = S @ h1 + gb1
    k_agg<2><<<NNODE, 256, 0, stream>>>(row_start, elist, srcA, dinv, bufA, gb1, bufB);
    // h2 = g1 @ gw2
    k_gemm<<<dim3(256 / 64, NNODE / 64), 256, 0, stream>>>(
        bufB, 512, nullptr, 0, gw2, 256, nullptr, bufA, 256, 0);
    // g2 = S @ h2 + gb2
    k_agg<1><<<NNODE, 256, 0, stream>>>(row_start, elist, srcA, dinv, bufA, gb2, bufC);
    // l1 = relu(x_self @ w_in_self + b_in_self)
    k_gemm<<<dim3(512 / 64, NNODE / 64), 256, 0, stream>>>(
        x_self, 512, nullptr, 0, w_in_self, 512, b_in_self, bufA, 512, 1);
    // z[:, :256] = [x_self | l1] @ w_out_self + b_out_self
    k_gemm<<<dim3(256 / 64, NNODE / 64), 256, 0, stream>>>(
        x_self, 512, bufA, 512, w_out_self, 256, b_out_self, z, 512, 0);
    // z[:, 256:] = [x_neighbor | g2] @ w_out + b_out
    k_gemm<<<dim3(256 / 64, NNODE / 64), 256, 0, stream>>>(
        x_neighbor, 512, bufC, 256, w_out, 256, b_out, z + 256, 512, 0);

    // split z -> bf16 hi/lo (bufA is free now), then MFMA zz^T
    k_split<<<(NNODE * 512 / 4) / 256, 256, 0, stream>>>(z, zhi, zlo);
    k_zzt_mfma<<<64 * 65 / 2, 256, 0, stream>>>(zhi, zlo, out);
}

// Round 3
// 531.310 us; speedup vs baseline: 1.9683x; 1.2878x over previous
//
#include <hip/hip_runtime.h>
#include <cstdint>
#include <cstddef>

#define NNODE 8192
#define NEDGE 262144

typedef __attribute__((ext_vector_type(8))) short bf16x8;
typedef __attribute__((ext_vector_type(4))) float f32x4;

// ---------------- bf16 split helpers ----------------
__device__ __forceinline__ unsigned short f2bf_rn(float x) {
    unsigned u = __float_as_uint(x);
    u = (u + 0x7FFFu + ((u >> 16) & 1u)) >> 16;
    return (unsigned short)u;
}
__device__ __forceinline__ float bf2f(unsigned short h) {
    return __uint_as_float(((unsigned)h) << 16);
}

// ---------------- utility kernels ----------------

__global__ void k_zero_int(int* p, int n) {
    int i = blockIdx.x * blockDim.x + threadIdx.x;
    if (i < n) p[i] = 0;
}

__global__ void k_count(const int* __restrict__ dst, int* __restrict__ cnt, int n) {
    int i = blockIdx.x * blockDim.x + threadIdx.x;
    if (i < n) atomicAdd(&cnt[dst[i]], 1);
}

// single block: exclusive scan of cnt[8192] -> row_start/cursor, dinv = rsqrt(deg+1)
__global__ __launch_bounds__(256) void k_scan(const int* __restrict__ cnt,
                                              int* __restrict__ row_start,
                                              int* __restrict__ cursor,
                                              float* __restrict__ dinv) {
    __shared__ int part[256];
    const int tid = threadIdx.x;
    const int PER = NNODE / 256;  // 32
    const int base = tid * PER;
    int loc[PER];
    int sum = 0;
#pragma unroll
    for (int i = 0; i < PER; ++i) { loc[i] = cnt[base + i]; sum += loc[i]; }
    part[tid] = sum;
    __syncthreads();
    if (tid == 0) {
        int r = 0;
        for (int i = 0; i < 256; ++i) { int t = part[i]; part[i] = r; r += t; }
    }
    __syncthreads();
    int run = part[tid];
#pragma unroll
    for (int i = 0; i < PER; ++i) {
        row_start[base + i] = run;
        cursor[base + i] = run;
        dinv[base + i] = rsqrtf((float)loc[i] + 1.0f);  // deg = in-degree + self loop
        run += loc[i];
    }
    if (tid == 255) row_start[NNODE] = run;
}

__global__ void k_fill_csr(const int* __restrict__ dst, int* __restrict__ cursor,
                           int* __restrict__ elist, int n) {
    int e = blockIdx.x * blockDim.x + threadIdx.x;
    if (e < n) {
        int pos = atomicAdd(&cursor[dst[e]], 1);
        elist[pos] = e;
    }
}

// ---------------- split fp32 row-major -> hi/lo bf16 (same layout) ----------------
__global__ __launch_bounds__(256) void k_split(const float* __restrict__ z,
                                               unsigned short* __restrict__ hi,
                                               unsigned short* __restrict__ lo) {
    const int i = blockIdx.x * blockDim.x + threadIdx.x;  // 4 floats per thread
    float4 v = ((const float4*)z)[i];
    float x[4] = {v.x, v.y, v.z, v.w};
    unsigned short h[4], l[4];
#pragma unroll
    for (int j = 0; j < 4; ++j) {
        h[j] = f2bf_rn(x[j]);
        l[j] = f2bf_rn(x[j] - bf2f(h[j]));
    }
    ((ushort4*)hi)[i] = make_ushort4(h[0], h[1], h[2], h[3]);
    ((ushort4*)lo)[i] = make_ushort4(l[0], l[1], l[2], l[3]);
}

// ---------------- split + transpose weight: W[K,N] fp32 -> Wt_hi/lo [N,K] bf16 ----------------
// 32x32 LDS tile, 256 threads (32 cols x 8 rows x 4 iters). Grid (K/32, N/32).
__global__ __launch_bounds__(256) void k_split_wt(const float* __restrict__ W, int K, int N,
                                                  unsigned short* __restrict__ Wth,
                                                  unsigned short* __restrict__ Wtl) {
    __shared__ float t[32][33];
    const int k0 = blockIdx.x * 32, n0 = blockIdx.y * 32;
    const int c = threadIdx.x & 31, r8 = threadIdx.x >> 5;
#pragma unroll
    for (int i = 0; i < 4; ++i) {
        int r = r8 + i * 8;
        t[r][c] = W[(size_t)(k0 + r) * N + n0 + c];
    }
    __syncthreads();
#pragma unroll
    for (int i = 0; i < 4; ++i) {
        int r = r8 + i * 8;  // local n
        float x = t[c][r];   // = W[k0+c][n0+r]
        unsigned short h = f2bf_rn(x);
        unsigned short l = f2bf_rn(x - bf2f(h));
        Wth[(size_t)(n0 + r) * K + k0 + c] = h;
        Wtl[(size_t)(n0 + r) * K + k0 + c] = l;
    }
}

// ---------------- generic split-bf16 MFMA GEMM ----------------
// C[M,N] = act( [A1 | A2] @ W + bias ),  W supplied transposed: Wt[N, Ktot] (hi/lo bf16).
// BM=BN=64, BK=32, 4 waves (wave w owns rows w*16..+15, all 64 cols).
// score = hi*hi + hi*lo + lo*hi (lo*lo dropped, ~2^-18 rel).
// Staging: global_load_lds w=16, pre-swizzled source slot, XOR-swizzled ds_read.
// Epilogue modes: Cf!=null -> fp32; else split bf16 into Ch/Cl.
__global__ __launch_bounds__(256) void k_gemm_mfma(
    const unsigned short* __restrict__ A1h, const unsigned short* __restrict__ A1l, int K1,
    const unsigned short* __restrict__ A2h, const unsigned short* __restrict__ A2l, int K2,
    const unsigned short* __restrict__ Wth, const unsigned short* __restrict__ Wtl, int Ktot,
    const float* __restrict__ bias, int relu,
    float* __restrict__ Cf, unsigned short* __restrict__ Ch, unsigned short* __restrict__ Cl,
    int ldc) {
    __shared__ __align__(16) char smem[16384];  // sAh | sAl | sBh | sBl, 4KB each (64 rows x 64B)
    const int tid = threadIdx.x;
    const int lane = tid & 63;
    const int w = tid >> 6;
    const int bm = blockIdx.y * 64;
    const int bn = blockIdx.x * 64;
    const int rstage = w * 16 + (lane >> 2);                    // tile row staged by this lane
    const int swz_src = ((lane & 3) ^ ((lane >> 2) & 3)) * 16;  // pre-swizzled source slot
    const int sread = ((lane >> 4) ^ (lane & 3)) * 16;          // swizzled read slot

    f32x4 acc[4] = {};

    for (int k0 = 0; k0 < Ktot; k0 += 32) {
        const char *Ah, *Al;
        size_t rowb;
        int kb;
        if (k0 < K1) { Ah = (const char*)A1h; Al = (const char*)A1l; rowb = (size_t)K1 * 2; kb = k0 * 2; }
        else         { Ah = (const char*)A2h; Al = (const char*)A2l; rowb = (size_t)K2 * 2; kb = (k0 - K1) * 2; }
        const char* ga_h = Ah + (size_t)(bm + rstage) * rowb + kb + swz_src;
        const char* ga_l = Al + (size_t)(bm + rstage) * rowb + kb + swz_src;
        const char* gb_h = (const char*)Wth + (size_t)(bn + rstage) * (Ktot * 2) + k0 * 2 + swz_src;
        const char* gb_l = (const char*)Wtl + (size_t)(bn + rstage) * (Ktot * 2) + k0 * 2 + swz_src;
        char* lb = smem + w * 1024;  // wave-uniform; HW appends lane*16
        __builtin_amdgcn_global_load_lds((const __attribute__((address_space(1))) void*)ga_h,
                                         (__attribute__((address_space(3))) void*)(lb), 16, 0, 0);
        __builtin_amdgcn_global_load_lds((const __attribute__((address_space(1))) void*)ga_l,
                                         (__attribute__((address_space(3))) void*)(lb + 4096), 16, 0, 0);
        __builtin_amdgcn_global_load_lds((const __attribute__((address_space(1))) void*)gb_h,
                                         (__attribute__((address_space(3))) void*)(lb + 8192), 16, 0, 0);
        __builtin_amdgcn_global_load_lds((const __attribute__((address_space(1))) void*)gb_l,
                                         (__attribute__((address_space(3))) void*)(lb + 12288), 16, 0, 0);
        __syncthreads();

        bf16x8 ah, al, bh[4], bl[4];
        const char* pa = smem + (w * 16 + (lane & 15)) * 64 + sread;
        ah = *(const bf16x8*)pa;
        al = *(const bf16x8*)(pa + 4096);
        const char* pb = smem + 8192 + (lane & 15) * 64 + sread;
#pragma unroll
        for (int n = 0; n < 4; ++n) {
            bh[n] = *(const bf16x8*)(pb + n * 1024);
            bl[n] = *(const bf16x8*)(pb + 4096 + n * 1024);
        }
#pragma unroll
        for (int n = 0; n < 4; ++n) {
            acc[n] = __builtin_amdgcn_mfma_f32_16x16x32_bf16(ah, bh[n], acc[n], 0, 0, 0);
            acc[n] = __builtin_amdgcn_mfma_f32_16x16x32_bf16(ah, bl[n], acc[n], 0, 0, 0);
            acc[n] = __builtin_amdgcn_mfma_f32_16x16x32_bf16(al, bh[n], acc[n], 0, 0, 0);
        }
        __syncthreads();
    }

    // epilogue: C/D layout col=lane&15, row=(lane>>4)*4+reg
    const int rj = (lane >> 4) * 4;
    const int cc = lane & 15;
#pragma unroll
    for (int n = 0; n < 4; ++n) {
        const int col = bn + n * 16 + cc;
        const float bv = bias ? bias[col] : 0.0f;
#pragma unroll
        for (int j = 0; j < 4; ++j) {
            float x = acc[n][j] + bv;
            if (relu) x = fmaxf(x, 0.0f);
            const int row = bm + w * 16 + rj + j;
            if (Cf) {
                Cf[(size_t)row * ldc + col] = x;
            } else {
                unsigned short h = f2bf_rn(x);
                Ch[(size_t)row * ldc + col] = h;
                Cl[(size_t)row * ldc + col] = f2bf_rn(x - bf2f(h));
            }
        }
    }
}

// ---------------- GCN aggregation (gather over CSR-by-dst), split-bf16 output ----------------
template <int CPT>
__global__ __launch_bounds__(256) void k_agg(
    const int* __restrict__ row_start, const int* __restrict__ elist,
    const int* __restrict__ srcArr, const float* __restrict__ dinv,
    const float* __restrict__ h, const float* __restrict__ bias,
    unsigned short* __restrict__ out_hi, unsigned short* __restrict__ out_lo) {
    const int D = 256 * CPT;
    const int n = blockIdx.x;
    const int c = threadIdx.x;
    const float di = dinv[n];
    float acc[CPT];
#pragma unroll
    for (int i = 0; i < CPT; ++i)
        acc[i] = di * di * h[(size_t)n * D + c + i * 256] + bias[c + i * 256];
    const int s0 = row_start[n], s1 = row_start[n + 1];
    for (int j = s0; j < s1; ++j) {
        int e = elist[j];
        int s = srcArr[e];
        float w = dinv[s] * di;
#pragma unroll
        for (int i = 0; i < CPT; ++i)
            acc[i] += w * h[(size_t)s * D + c + i * 256];
    }
#pragma unroll
    for (int i = 0; i < CPT; ++i) {
        unsigned short hb = f2bf_rn(acc[i]);
        out_hi[(size_t)n * D + c + i * 256] = hb;
        out_lo[(size_t)n * D + c + i * 256] = f2bf_rn(acc[i] - bf2f(hb));
    }
}

// ---------------- out = sigmoid(Z Z^T) via split-bf16 MFMA (unchanged) ----------------
__global__ __launch_bounds__(256) void k_zzt_mfma(const unsigned short* __restrict__ zhi,
                                                  const unsigned short* __restrict__ zlo,
                                                  float* __restrict__ out) {
    __shared__ __align__(16) char smem[32768];
    const int tid = threadIdx.x;
    const int lane = tid & 63;
    const int w = tid >> 6;
    const int wr = w >> 1, wc = w & 1;

    const int t = blockIdx.x;
    int bi = (int)((sqrtf(8.0f * (float)t + 1.0f) - 1.0f) * 0.5f);
    while ((bi + 1) * (bi + 2) / 2 <= t) ++bi;
    while (bi * (bi + 1) / 2 > t) --bi;
    const int bj = t - bi * (bi + 1) / 2;

    const char* srcs[4];
    srcs[0] = (const char*)zhi + (size_t)(bi * 128) * 1024;
    srcs[1] = (const char*)zlo + (size_t)(bi * 128) * 1024;
    srcs[2] = (const char*)zhi + (size_t)(bj * 128) * 1024;
    srcs[3] = (const char*)zlo + (size_t)(bj * 128) * 1024;

    const int rloc = w * 16 + (lane >> 2);
    const int swz_src = ((lane & 3) ^ ((lane >> 2) & 3)) * 16;
    const int sread = ((lane >> 4) ^ (lane & 3)) * 16;

    f32x4 acc[4][4] = {};

    for (int k0 = 0; k0 < 512; k0 += 32) {
        const int kbyte = k0 * 2;
#pragma unroll
        for (int tile = 0; tile < 4; ++tile) {
#pragma unroll
            for (int i = 0; i < 2; ++i) {
                const char* gp = srcs[tile] + (size_t)(rloc + i * 64) * 1024 + kbyte + swz_src;
                char* lp = smem + tile * 8192 + i * 4096 + w * 1024;
                __builtin_amdgcn_global_load_lds(
                    (const __attribute__((address_space(1))) void*)gp,
                    (__attribute__((address_space(3))) void*)lp, 16, 0, 0);
            }
        }
        __syncthreads();

        bf16x8 ah[4], al[4], bh[4], bl[4];
        const char* pa = smem + (wr * 64 + (lane & 15)) * 64 + sread;
        const char* pb = smem + 16384 + (wc * 64 + (lane & 15)) * 64 + sread;
#pragma unroll
        for (int m = 0; m < 4; ++m) {
            ah[m] = *(const bf16x8*)(pa + m * 1024);
            al[m] = *(const bf16x8*)(pa + 8192 + m * 1024);
        }
#pragma unroll
        for (int n = 0; n < 4; ++n) {
            bh[n] = *(const bf16x8*)(pb + n * 1024);
            bl[n] = *(const bf16x8*)(pb + 8192 + n * 1024);
        }
#pragma unroll
        for (int m = 0; m < 4; ++m)
#pragma unroll
            for (int n = 0; n < 4; ++n) {
                acc[m][n] = __builtin_amdgcn_mfma_f32_16x16x32_bf16(ah[m], bh[n], acc[m][n], 0, 0, 0);
                acc[m][n] = __builtin_amdgcn_mfma_f32_16x16x32_bf16(ah[m], bl[n], acc[m][n], 0, 0, 0);
                acc[m][n] = __builtin_amdgcn_mfma_f32_16x16x32_bf16(al[m], bh[n], acc[m][n], 0, 0, 0);
            }
        __syncthreads();
    }

    const int rj = (lane >> 4) * 4;
    const int cc = lane & 15;
#pragma unroll
    for (int m = 0; m < 4; ++m) {
#pragma unroll
        for (int n = 0; n < 4; ++n) {
            float s[4];
#pragma unroll
            for (int j = 0; j < 4; ++j)
                s[j] = 1.0f / (1.0f + __expf(-acc[m][n][j]));
            const int gr0 = bi * 128 + wr * 64 + m * 16 + rj;
            const int gc  = bj * 128 + wc * 64 + n * 16 + cc;
#pragma unroll
            for (int j = 0; j < 4; ++j)
                out[(size_t)(gr0 + j) * NNODE + gc] = s[j];
            if (bi != bj) {
                const int mr = bj * 128 + wc * 64 + n * 16 + cc;
                const int mc = bi * 128 + wr * 64 + m * 16 + rj;
                *(float4*)(out + (size_t)mr * NNODE + mc) = make_float4(s[0], s[1], s[2], s[3]);
            }
        }
    }
}

// ---------------- launch ----------------
extern "C" void kernel_launch(void* const* d_in, const int* in_sizes, int n_in,
                              void* d_out, int out_size, void* d_ws, size_t ws_size,
                              hipStream_t stream) {
    const float* x_self     = (const float*)d_in[0];
    const float* x_neighbor = (const float*)d_in[1];
    const int*   ei         = (const int*)d_in[2];
    const float* w_in_self  = (const float*)d_in[3];
    const float* b_in_self  = (const float*)d_in[4];
    const float* w_out_self = (const float*)d_in[5];
    const float* b_out_self = (const float*)d_in[6];
    const float* gw1        = (const float*)d_in[7];
    const float* gb1        = (const float*)d_in[8];
    const float* gw2        = (const float*)d_in[9];
    const float* gb2        = (const float*)d_in[10];
    const float* w_out      = (const float*)d_in[11];
    const float* b_out      = (const float*)d_in[12];
    float* out = (float*)d_out;

    char* ws = (char*)d_ws;
    const size_t MB = 1024 * 1024;
    // 0-2 MB: CSR
    int*   cnt       = (int*)(ws + 0);
    int*   row_start = (int*)(ws + 32 * 1024);
    int*   cursor    = (int*)(ws + 68 * 1024);
    int*   elist     = (int*)(ws + 100 * 1024);
    float* dinv      = (float*)(ws + 100 * 1024 + MB);
    // activations (split bf16 unless noted)
    unsigned short* xsh = (unsigned short*)(ws + 2 * MB);    // 8 MB
    unsigned short* xsl = (unsigned short*)(ws + 10 * MB);
    unsigned short* xnh = (unsigned short*)(ws + 18 * MB);
    unsigned short* xnl = (unsigned short*)(ws + 26 * MB);
    float*          h1  = (float*)(ws + 34 * MB);            // 16 MB fp32
    unsigned short* g1h = (unsigned short*)(ws + 50 * MB);
    unsigned short* g1l = (unsigned short*)(ws + 58 * MB);
    float*          h2  = (float*)(ws + 66 * MB);            // 8 MB fp32
    unsigned short* g2h = (unsigned short*)(ws + 74 * MB);   // 4 MB
    unsigned short* g2l = (unsigned short*)(ws + 78 * MB);
    unsigned short* l1h = (unsigned short*)(ws + 82 * MB);
    unsigned short* l1l = (unsigned short*)(ws + 90 * MB);
    unsigned short* zhi = (unsigned short*)(ws + 98 * MB);
    unsigned short* zlo = (unsigned short*)(ws + 106 * MB);
    // weights, transposed+split
    unsigned short* gw1t_h = (unsigned short*)(ws + 114 * MB);
    unsigned short* gw1t_l = (unsigned short*)(ws + 114 * MB + 512 * 1024);
    unsigned short* wint_h = (unsigned short*)(ws + 115 * MB);
    unsigned short* wint_l = (unsigned short*)(ws + 115 * MB + 512 * 1024);
    unsigned short* wost_h = (unsigned short*)(ws + 116 * MB);
    unsigned short* wost_l = (unsigned short*)(ws + 116 * MB + 512 * 1024);
    unsigned short* gw2t_h = (unsigned short*)(ws + 117 * MB);
    unsigned short* gw2t_l = (unsigned short*)(ws + 117 * MB + 512 * 1024);
    unsigned short* wot_h  = (unsigned short*)(ws + 118 * MB);
    unsigned short* wot_l  = (unsigned short*)(ws + 118 * MB + 512 * 1024);

    const int* srcA = ei;          // edge_index[0]
    const int* dstA = ei + NEDGE;  // edge_index[1]

    // CSR build (by dst) + degree norm
    k_zero_int<<<NNODE / 256, 256, 0, stream>>>(cnt, NNODE);
    k_count<<<NEDGE / 256, 256, 0, stream>>>(dstA, cnt, NEDGE);
    k_scan<<<1, 256, 0, stream>>>(cnt, row_start, cursor, dinv);
    k_fill_csr<<<NEDGE / 256, 256, 0, stream>>>(dstA, cursor, elist, NEDGE);

    // split activations & weights
    k_split<<<(NNODE * 512 / 4) / 256, 256, 0, stream>>>(x_self, xsh, xsl);
    k_split<<<(NNODE * 512 / 4) / 256, 256, 0, stream>>>(x_neighbor, xnh, xnl);
    k_split_wt<<<dim3(512 / 32, 512 / 32), 256, 0, stream>>>(gw1, 512, 512, gw1t_h, gw1t_l);
    k_split_wt<<<dim3(512 / 32, 512 / 32), 256, 0, stream>>>(w_in_self, 512, 512, wint_h, wint_l);
    k_split_wt<<<dim3(1024 / 32, 256 / 32), 256, 0, stream>>>(w_out_self, 1024, 256, wost_h, wost_l);
    k_split_wt<<<dim3(512 / 32, 256 / 32), 256, 0, stream>>>(gw2, 512, 256, gw2t_h, gw2t_l);
    k_split_wt<<<dim3(768 / 32, 256 / 32), 256, 0, stream>>>(w_out, 768, 256, wot_h, wot_l);

    // h1 = x_self @ gw1 (fp32 out)
    k_gemm_mfma<<<dim3(8, 128), 256, 0, stream>>>(
        xsh, xsl, 512, nullptr, nullptr, 0, gw1t_h, gw1t_l, 512,
        nullptr, 0, h1, nullptr, nullptr, 512);
    // g1 = S @ h1 + gb1 (split out)
    k_agg<2><<<NNODE, 256, 0, stream>>>(row_start, elist, srcA, dinv, h1, gb1, g1h, g1l);
    // h2 = g1 @ gw2 (fp32 out)
    k_gemm_mfma<<<dim3(4, 128), 256, 0, stream>>>(
        g1h, g1l, 512, nullptr, nullptr, 0, gw2t_h, gw2t_l, 512,
        nullptr, 0, h2, nullptr, nullptr, 256);
    // g2 = S @ h2 + gb2 (split out)
    k_agg<1><<<NNODE, 256, 0, stream>>>(row_start, elist, srcA, dinv, h2, gb2, g2h, g2l);
    // l1 = relu(x_self @ w_in_self + b_in_self) (split out)
    k_gemm_mfma<<<dim3(8, 128), 256, 0, stream>>>(
        xsh, xsl, 512, nullptr, nullptr, 0, wint_h, wint_l, 512,
        b_in_self, 1, nullptr, l1h, l1l, 512);
    // z[:, :256] = [x_self | l1] @ w_out_self + b_out_self (split out into z)
    k_gemm_mfma<<<dim3(4, 128), 256, 0, stream>>>(
        xsh, xsl, 512, l1h, l1l, 512, wost_h, wost_l, 1024,
        b_out_self, 0, nullptr, zhi, zlo, 512);
    // z[:, 256:] = [x_neighbor | g2] @ w_out + b_out (split out into z cols 256..511)
    k_gemm_mfma<<<dim3(4, 128), 256, 0, stream>>>(
        xnh, xnl, 512, g2h, g2l, 256, wot_h, wot_l, 768,
        b_out, 0, nullptr, zhi + 256, zlo + 256, 512);
    // out = sigmoid(z z^T)
    k_zzt_mfma<<<64 * 65 / 2, 256, 0, stream>>>(zhi, zlo, out);
}

// Round 4
// 520.206 us; speedup vs baseline: 2.0104x; 1.0213x over previous
//
#include <hip/hip_runtime.h>
#include <cstdint>
#include <cstddef>

#define NNODE 8192
#define NEDGE 262144

typedef __attribute__((ext_vector_type(8))) short bf16x8;
typedef __attribute__((ext_vector_type(4))) float f32x4;
typedef unsigned short ushort_t;

// ---------------- bf16 split helpers ----------------
__device__ __forceinline__ unsigned short f2bf_rn(float x) {
    unsigned u = __float_as_uint(x);
    u = (u + 0x7FFFu + ((u >> 16) & 1u)) >> 16;
    return (unsigned short)u;
}
__device__ __forceinline__ float bf2f(unsigned short h) {
    return __uint_as_float(((unsigned)h) << 16);
}

// ---------------- utility kernels ----------------

__global__ void k_zero_int(int* p, int n) {
    int i = blockIdx.x * blockDim.x + threadIdx.x;
    if (i < n) p[i] = 0;
}

__global__ void k_count(const int* __restrict__ dst, int* __restrict__ cnt, int n) {
    int i = blockIdx.x * blockDim.x + threadIdx.x;
    if (i < n) atomicAdd(&cnt[dst[i]], 1);
}

// single block: exclusive scan of cnt[8192] -> row_start/cursor, dinv = rsqrt(deg+1)
__global__ __launch_bounds__(256) void k_scan(const int* __restrict__ cnt,
                                              int* __restrict__ row_start,
                                              int* __restrict__ cursor,
                                              float* __restrict__ dinv) {
    __shared__ int part[256];
    const int tid = threadIdx.x;
    const int PER = NNODE / 256;  // 32
    const int base = tid * PER;
    int loc[PER];
    int sum = 0;
#pragma unroll
    for (int i = 0; i < PER; ++i) { loc[i] = cnt[base + i]; sum += loc[i]; }
    part[tid] = sum;
    __syncthreads();
    if (tid == 0) {
        int r = 0;
        for (int i = 0; i < 256; ++i) { int t = part[i]; part[i] = r; r += t; }
    }
    __syncthreads();
    int run = part[tid];
#pragma unroll
    for (int i = 0; i < PER; ++i) {
        row_start[base + i] = run;
        cursor[base + i] = run;
        dinv[base + i] = rsqrtf((float)loc[i] + 1.0f);  // deg = in-degree + self loop
        run += loc[i];
    }
    if (tid == 255) row_start[NNODE] = run;
}

// fill CSR with (src, norm-weight) directly
__global__ void k_fill_csr2(const int* __restrict__ src, const int* __restrict__ dst,
                            int* __restrict__ cursor, const float* __restrict__ dinv,
                            int* __restrict__ slist, float* __restrict__ wlist, int n) {
    int e = blockIdx.x * blockDim.x + threadIdx.x;
    if (e < n) {
        int d = dst[e];
        int s = src[e];
        int pos = atomicAdd(&cursor[d], 1);
        slist[pos] = s;
        wlist[pos] = dinv[s] * dinv[d];
    }
}

// s_i = dinv_i^2 + sum_row wlist  ( = (S_hat @ 1)_i )
__global__ void k_rowsum(const int* __restrict__ row_start, const float* __restrict__ wlist,
                         const float* __restrict__ dinv, float* __restrict__ svec) {
    int i = blockIdx.x * blockDim.x + threadIdx.x;
    if (i < NNODE) {
        float a = dinv[i] * dinv[i];
        const int e0 = row_start[i], e1 = row_start[i + 1];
        for (int j = e0; j < e1; ++j) a += wlist[j];
        svec[i] = a;
    }
}

// bc[n] = sum_c gb1[c] * gw2[c][n]   (one block, 256 threads)
__global__ __launch_bounds__(256) void k_bc(const float* __restrict__ gb1,
                                            const float* __restrict__ gw2,
                                            float* __restrict__ bc) {
    const int nn = threadIdx.x;
    float a = 0.0f;
    for (int c = 0; c < 512; ++c) a += gb1[c] * gw2[c * 256 + nn];
    bc[nn] = a;
}

// ---------------- small fp32 VALU GEMM (for Wc = W1 @ W2 only) ----------------
__global__ __launch_bounds__(256) void k_gemm_f32(
    const float* __restrict__ A, int K,
    const float* __restrict__ W, int N,
    float* __restrict__ C, int ldc) {
    __shared__ float sA[16][68];
    __shared__ float sB[16][68];
    const int tid = threadIdx.x;
    const int tx = tid & 15, ty = tid >> 4;
    const int bm = blockIdx.y * 64;
    const int bn = blockIdx.x * 64;
    const int arow = tid >> 2, ac4 = (tid & 3) * 4;
    const int brow = tid >> 4, bc4 = (tid & 15) * 4;
    float acc[4][4] = {};
    for (int k0 = 0; k0 < K; k0 += 16) {
        float4 va = *(const float4*)(A + (size_t)(bm + arow) * K + k0 + ac4);
        float4 vb = *(const float4*)(W + (size_t)(k0 + brow) * N + bn + bc4);
        sA[ac4 + 0][arow] = va.x; sA[ac4 + 1][arow] = va.y;
        sA[ac4 + 2][arow] = va.z; sA[ac4 + 3][arow] = va.w;
        *(float4*)&sB[brow][bc4] = vb;
        __syncthreads();
#pragma unroll
        for (int kk = 0; kk < 16; ++kk) {
            float av[4], bv[4];
            *(float4*)av = *(const float4*)&sA[kk][ty * 4];
            *(float4*)bv = *(const float4*)&sB[kk][tx * 4];
#pragma unroll
            for (int i = 0; i < 4; ++i)
#pragma unroll
                for (int j = 0; j < 4; ++j) acc[i][j] += av[i] * bv[j];
        }
        __syncthreads();
    }
#pragma unroll
    for (int i = 0; i < 4; ++i)
        *(float4*)(C + (size_t)(bm + ty * 4 + i) * ldc + bn + tx * 4) =
            make_float4(acc[i][0], acc[i][1], acc[i][2], acc[i][3]);
}

// ---------------- split fp32 row-major -> hi/lo bf16 ----------------
__global__ __launch_bounds__(256) void k_split(const float* __restrict__ z,
                                               unsigned short* __restrict__ hi,
                                               unsigned short* __restrict__ lo) {
    const int i = blockIdx.x * blockDim.x + threadIdx.x;
    float4 v = ((const float4*)z)[i];
    float x[4] = {v.x, v.y, v.z, v.w};
    unsigned short h[4], l[4];
#pragma unroll
    for (int j = 0; j < 4; ++j) {
        h[j] = f2bf_rn(x[j]);
        l[j] = f2bf_rn(x[j] - bf2f(h[j]));
    }
    ((ushort4*)hi)[i] = make_ushort4(h[0], h[1], h[2], h[3]);
    ((ushort4*)lo)[i] = make_ushort4(l[0], l[1], l[2], l[3]);
}

// ---------------- split + transpose weight: W[K,N] fp32 -> Wt_hi/lo [N,K] bf16 ----------------
__global__ __launch_bounds__(256) void k_split_wt(const float* __restrict__ W, int K, int N,
                                                  unsigned short* __restrict__ Wth,
                                                  unsigned short* __restrict__ Wtl) {
    __shared__ float t[32][33];
    const int k0 = blockIdx.x * 32, n0 = blockIdx.y * 32;
    const int c = threadIdx.x & 31, r8 = threadIdx.x >> 5;
#pragma unroll
    for (int i = 0; i < 4; ++i) {
        int r = r8 + i * 8;
        t[r][c] = W[(size_t)(k0 + r) * N + n0 + c];
    }
    __syncthreads();
#pragma unroll
    for (int i = 0; i < 4; ++i) {
        int r = r8 + i * 8;
        float x = t[c][r];
        unsigned short h = f2bf_rn(x);
        unsigned short l = f2bf_rn(x - bf2f(h));
        Wth[(size_t)(n0 + r) * K + k0 + c] = h;
        Wtl[(size_t)(n0 + r) * K + k0 + c] = l;
    }
}

// ---------------- generic split-bf16 MFMA GEMM, BM=128 BN=64 BK=32, 4 waves ----------------
// C[M,N] = act( [A1 | A2] @ W + bias ), W transposed: Wt[N, Ktot] hi/lo bf16.
// Wave w owns rows w*32..w*32+31, all 64 cols (acc 2x4). 24 MFMA : 12 ds_read per step.
// Columns < N1: (optional relu) split-bf16 out to C1h/C1l (ldc1).
// Columns >= N1: fp32 out to C2f at col-N1 (ldc2), no bias.
__global__ __launch_bounds__(256) void k_gemm_mfma(
    const unsigned short* __restrict__ A1h, const unsigned short* __restrict__ A1l, int K1,
    const unsigned short* __restrict__ A2h, const unsigned short* __restrict__ A2l, int K2,
    const unsigned short* __restrict__ Wth, const unsigned short* __restrict__ Wtl, int Ktot,
    const float* __restrict__ bias1, int relu1,
    unsigned short* __restrict__ C1h, unsigned short* __restrict__ C1l, int ldc1, int N1,
    float* __restrict__ C2f, int ldc2) {
    // LDS image: Ah[128][64B] @0 | Al @8192 | Bh[64][64B] @16384 | Bl @20480
    __shared__ __align__(16) char smem[24576];
    const int tid = threadIdx.x;
    const int lane = tid & 63;
    const int w = tid >> 6;
    const int bm = blockIdx.y * 128;
    const int bn = blockIdx.x * 64;
    const int crow = lane >> 2;                                 // row within 16-row chunk
    const int swz_src = ((lane & 3) ^ ((lane >> 2) & 3)) * 16;  // pre-swizzled source slot
    const int sread = ((lane >> 4) ^ (lane & 3)) * 16;          // swizzled read slot
    const size_t wrowb = (size_t)Ktot * 2;

    f32x4 acc[2][4] = {};

    for (int k0 = 0; k0 < Ktot; k0 += 32) {
        const char *Ah, *Al;
        size_t rowbA;
        int kbA;
        if (k0 < K1) { Ah = (const char*)A1h; Al = (const char*)A1l; rowbA = (size_t)K1 * 2; kbA = k0 * 2; }
        else         { Ah = (const char*)A2h; Al = (const char*)A2l; rowbA = (size_t)K2 * 2; kbA = (k0 - K1) * 2; }
        const int kbW = k0 * 2;
#pragma unroll
        for (int i = 0; i < 6; ++i) {
            const int k = w * 6 + i;  // chunk id 0..23, wave-uniform
            char* lp = smem + k * 1024;
            const char* gp;
            if (k < 8) {
                gp = Ah + (size_t)(bm + k * 16 + crow) * rowbA + kbA + swz_src;
            } else if (k < 16) {
                gp = Al + (size_t)(bm + (k - 8) * 16 + crow) * rowbA + kbA + swz_src;
            } else if (k < 20) {
                gp = (const char*)Wth + (size_t)(bn + (k - 16) * 16 + crow) * wrowb + kbW + swz_src;
            } else {
                gp = (const char*)Wtl + (size_t)(bn + (k - 20) * 16 + crow) * wrowb + kbW + swz_src;
            }
            __builtin_amdgcn_global_load_lds((const __attribute__((address_space(1))) void*)gp,
                                             (__attribute__((address_space(3))) void*)lp, 16, 0, 0);
        }
        __syncthreads();

        bf16x8 ah[2], al[2], bh[4], bl[4];
#pragma unroll
        for (int m = 0; m < 2; ++m) {
            const int row = w * 32 + m * 16 + (lane & 15);
            ah[m] = *(const bf16x8*)(smem + row * 64 + sread);
            al[m] = *(const bf16x8*)(smem + 8192 + row * 64 + sread);
        }
#pragma unroll
        for (int n = 0; n < 4; ++n) {
            const int row = n * 16 + (lane & 15);
            bh[n] = *(const bf16x8*)(smem + 16384 + row * 64 + sread);
            bl[n] = *(const bf16x8*)(smem + 20480 + row * 64 + sread);
        }
#pragma unroll
        for (int m = 0; m < 2; ++m)
#pragma unroll
            for (int n = 0; n < 4; ++n) {
                acc[m][n] = __builtin_amdgcn_mfma_f32_16x16x32_bf16(ah[m], bh[n], acc[m][n], 0, 0, 0);
                acc[m][n] = __builtin_amdgcn_mfma_f32_16x16x32_bf16(ah[m], bl[n], acc[m][n], 0, 0, 0);
                acc[m][n] = __builtin_amdgcn_mfma_f32_16x16x32_bf16(al[m], bh[n], acc[m][n], 0, 0, 0);
            }
        __syncthreads();
    }

    // epilogue: C/D layout col=lane&15, row=(lane>>4)*4+reg
    const int rj = (lane >> 4) * 4;
    const int cc = lane & 15;
#pragma unroll
    for (int m = 0; m < 2; ++m) {
#pragma unroll
        for (int n = 0; n < 4; ++n) {
            const int col = bn + n * 16 + cc;
#pragma unroll
            for (int j = 0; j < 4; ++j) {
                const int row = bm + w * 32 + m * 16 + rj + j;
                float x = acc[m][n][j];
                if (col < N1) {
                    if (bias1) x += bias1[col];
                    if (relu1) x = fmaxf(x, 0.0f);
                    unsigned short h = f2bf_rn(x);
                    C1h[(size_t)row * ldc1 + col] = h;
                    C1l[(size_t)row * ldc1 + col] = f2bf_rn(x - bf2f(h));
                } else {
                    C2f[(size_t)row * ldc2 + (col - N1)] = x;
                }
            }
        }
    }
}

// ---------------- GCN aggregation, 256-wide, CSR(src,w) gather ----------------
// MODE 0: outf[n] = dinv_n^2*h[n] + sum w*h[s]            (fp32 out)
// MODE 1: x = agg + svec[n]*bc[c] + b2[c]; split-bf16 out
template <int MODE>
__global__ __launch_bounds__(256) void k_agg2(
    const int* __restrict__ row_start, const int* __restrict__ slist,
    const float* __restrict__ wlist, const float* __restrict__ dinv,
    const float* __restrict__ h,
    const float* __restrict__ svec, const float* __restrict__ bc,
    const float* __restrict__ b2,
    float* __restrict__ outf,
    unsigned short* __restrict__ oh, unsigned short* __restrict__ ol) {
    const int n = blockIdx.x;
    const int c = threadIdx.x;
    const float di = dinv[n];
    float acc = di * di * h[(size_t)n * 256 + c];
    const int e0 = row_start[n], e1 = row_start[n + 1];
    for (int j = e0; j < e1; ++j) {
        acc += wlist[j] * h[(size_t)slist[j] * 256 + c];
    }
    if (MODE == 0) {
        outf[(size_t)n * 256 + c] = acc;
    } else {
        float x = acc + svec[n] * bc[c] + b2[c];
        unsigned short hb = f2bf_rn(x);
        oh[(size_t)n * 256 + c] = hb;
        ol[(size_t)n * 256 + c] = f2bf_rn(x - bf2f(hb));
    }
}

// ---------------- out = sigmoid(Z Z^T) via split-bf16 MFMA (unchanged, proven) ----------------
__global__ __launch_bounds__(256) void k_zzt_mfma(const unsigned short* __restrict__ zhi,
                                                  const unsigned short* __restrict__ zlo,
                                                  float* __restrict__ out) {
    __shared__ __align__(16) char smem[32768];
    const int tid = threadIdx.x;
    const int lane = tid & 63;
    const int w = tid >> 6;
    const int wr = w >> 1, wc = w & 1;

    const int t = blockIdx.x;
    int bi = (int)((sqrtf(8.0f * (float)t + 1.0f) - 1.0f) * 0.5f);
    while ((bi + 1) * (bi + 2) / 2 <= t) ++bi;
    while (bi * (bi + 1) / 2 > t) --bi;
    const int bj = t - bi * (bi + 1) / 2;

    const char* srcs[4];
    srcs[0] = (const char*)zhi + (size_t)(bi * 128) * 1024;
    srcs[1] = (const char*)zlo + (size_t)(bi * 128) * 1024;
    srcs[2] = (const char*)zhi + (size_t)(bj * 128) * 1024;
    srcs[3] = (const char*)zlo + (size_t)(bj * 128) * 1024;

    const int rloc = w * 16 + (lane >> 2);
    const int swz_src = ((lane & 3) ^ ((lane >> 2) & 3)) * 16;
    const int sread = ((lane >> 4) ^ (lane & 3)) * 16;

    f32x4 acc[4][4] = {};

    for (int k0 = 0; k0 < 512; k0 += 32) {
        const int kbyte = k0 * 2;
#pragma unroll
        for (int tile = 0; tile < 4; ++tile) {
#pragma unroll
            for (int i = 0; i < 2; ++i) {
                const char* gp = srcs[tile] + (size_t)(rloc + i * 64) * 1024 + kbyte + swz_src;
                char* lp = smem + tile * 8192 + i * 4096 + w * 1024;
                __builtin_amdgcn_global_load_lds(
                    (const __attribute__((address_space(1))) void*)gp,
                    (__attribute__((address_space(3))) void*)lp, 16, 0, 0);
            }
        }
        __syncthreads();

        bf16x8 ah[4], al[4], bh[4], bl[4];
        const char* pa = smem + (wr * 64 + (lane & 15)) * 64 + sread;
        const char* pb = smem + 16384 + (wc * 64 + (lane & 15)) * 64 + sread;
#pragma unroll
        for (int m = 0; m < 4; ++m) {
            ah[m] = *(const bf16x8*)(pa + m * 1024);
            al[m] = *(const bf16x8*)(pa + 8192 + m * 1024);
        }
#pragma unroll
        for (int n = 0; n < 4; ++n) {
            bh[n] = *(const bf16x8*)(pb + n * 1024);
            bl[n] = *(const bf16x8*)(pb + 8192 + n * 1024);
        }
#pragma unroll
        for (int m = 0; m < 4; ++m)
#pragma unroll
            for (int n = 0; n < 4; ++n) {
                acc[m][n] = __builtin_amdgcn_mfma_f32_16x16x32_bf16(ah[m], bh[n], acc[m][n], 0, 0, 0);
                acc[m][n] = __builtin_amdgcn_mfma_f32_16x16x32_bf16(ah[m], bl[n], acc[m][n], 0, 0, 0);
                acc[m][n] = __builtin_amdgcn_mfma_f32_16x16x32_bf16(al[m], bh[n], acc[m][n], 0, 0, 0);
            }
        __syncthreads();
    }

    const int rj = (lane >> 4) * 4;
    const int cc = lane & 15;
#pragma unroll
    for (int m = 0; m < 4; ++m) {
#pragma unroll
        for (int n = 0; n < 4; ++n) {
            float s[4];
#pragma unroll
            for (int j = 0; j < 4; ++j)
                s[j] = 1.0f / (1.0f + __expf(-acc[m][n][j]));
            const int gr0 = bi * 128 + wr * 64 + m * 16 + rj;
            const int gc  = bj * 128 + wc * 64 + n * 16 + cc;
#pragma unroll
            for (int j = 0; j < 4; ++j)
                out[(size_t)(gr0 + j) * NNODE + gc] = s[j];
            if (bi != bj) {
                const int mr = bj * 128 + wc * 64 + n * 16 + cc;
                const int mc = bi * 128 + wr * 64 + m * 16 + rj;
                *(float4*)(out + (size_t)mr * NNODE + mc) = make_float4(s[0], s[1], s[2], s[3]);
            }
        }
    }
}

// ---------------- launch ----------------
extern "C" void kernel_launch(void* const* d_in, const int* in_sizes, int n_in,
                              void* d_out, int out_size, void* d_ws, size_t ws_size,
                              hipStream_t stream) {
    const float* x_self     = (const float*)d_in[0];
    const float* x_neighbor = (const float*)d_in[1];
    const int*   ei         = (const int*)d_in[2];
    const float* w_in_self  = (const float*)d_in[3];
    const float* b_in_self  = (const float*)d_in[4];
    const float* w_out_self = (const float*)d_in[5];
    const float* b_out_self = (const float*)d_in[6];
    const float* gw1        = (const float*)d_in[7];
    const float* gb1        = (const float*)d_in[8];
    const float* gw2        = (const float*)d_in[9];
    const float* gb2        = (const float*)d_in[10];
    const float* w_out      = (const float*)d_in[11];
    const float* b_out      = (const float*)d_in[12];
    float* out = (float*)d_out;

    char* ws = (char*)d_ws;
    const size_t MB = 1024 * 1024;
    const size_t KB = 1024;
    int*   cnt       = (int*)(ws + 0);
    int*   row_start = (int*)(ws + 32 * KB);
    int*   cursor    = (int*)(ws + 96 * KB);
    float* dinv      = (float*)(ws + 128 * KB);
    float* svec      = (float*)(ws + 160 * KB);
    float* bc        = (float*)(ws + 192 * KB);
    int*   slist     = (int*)(ws + 2 * MB);
    float* wlist     = (float*)(ws + 3 * MB);
    unsigned short* xsh = (unsigned short*)(ws + 4 * MB);
    unsigned short* xsl = (unsigned short*)(ws + 12 * MB);
    unsigned short* xnh = (unsigned short*)(ws + 20 * MB);
    unsigned short* xnl = (unsigned short*)(ws + 28 * MB);
    unsigned short* l1h = (unsigned short*)(ws + 36 * MB);
    unsigned short* l1l = (unsigned short*)(ws + 44 * MB);
    float*          hc  = (float*)(ws + 52 * MB);   // 8 MB fp32 [8192,256]
    float*          t1  = (float*)(ws + 60 * MB);   // 8 MB fp32
    unsigned short* g2h = (unsigned short*)(ws + 68 * MB);
    unsigned short* g2l = (unsigned short*)(ws + 72 * MB);
    unsigned short* zhi = (unsigned short*)(ws + 76 * MB);
    unsigned short* zlo = (unsigned short*)(ws + 84 * MB);
    float*          Wc  = (float*)(ws + 92 * MB);   // 0.5 MB [512,256]
    unsigned short* wAt_h = (unsigned short*)(ws + 93 * MB);  // [768,512]
    unsigned short* wAt_l = (unsigned short*)(ws + 94 * MB);
    unsigned short* wost_h = (unsigned short*)(ws + 96 * MB); // [256,1024]
    unsigned short* wost_l = (unsigned short*)(ws + 97 * MB);
    unsigned short* wot_h  = (unsigned short*)(ws + 98 * MB); // [256,768]
    unsigned short* wot_l  = (unsigned short*)(ws + 99 * MB);

    const int* srcA = ei;          // edge_index[0]
    const int* dstA = ei + NEDGE;  // edge_index[1]

    // --- CSR + norm ---
    k_zero_int<<<NNODE / 256, 256, 0, stream>>>(cnt, NNODE);
    k_count<<<NEDGE / 256, 256, 0, stream>>>(dstA, cnt, NEDGE);
    k_scan<<<1, 256, 0, stream>>>(cnt, row_start, cursor, dinv);
    k_fill_csr2<<<NEDGE / 256, 256, 0, stream>>>(srcA, dstA, cursor, dinv, slist, wlist, NEDGE);
    k_rowsum<<<NNODE / 256, 256, 0, stream>>>(row_start, wlist, dinv, svec);

    // --- input splits + weight prep ---
    k_split<<<(NNODE * 512 / 4) / 256, 256, 0, stream>>>(x_self, xsh, xsl);
    k_split<<<(NNODE * 512 / 4) / 256, 256, 0, stream>>>(x_neighbor, xnh, xnl);
    // Wc = gw1 @ gw2  (512x256, fp32), bc = gb1^T @ gw2
    k_gemm_f32<<<dim3(256 / 64, 512 / 64), 256, 0, stream>>>(gw1, 512, gw2, 256, Wc, 256);
    k_bc<<<1, 256, 0, stream>>>(gb1, gw2, bc);
    // wAt = [w_in_self | Wc] transposed+split -> [768, 512]
    k_split_wt<<<dim3(16, 16), 256, 0, stream>>>(w_in_self, 512, 512, wAt_h, wAt_l);
    k_split_wt<<<dim3(16, 8), 256, 0, stream>>>(Wc, 512, 256, wAt_h + 512 * 512, wAt_l + 512 * 512);
    k_split_wt<<<dim3(32, 8), 256, 0, stream>>>(w_out_self, 1024, 256, wost_h, wost_l);
    k_split_wt<<<dim3(24, 8), 256, 0, stream>>>(w_out, 768, 256, wot_h, wot_l);

    // --- fused GEMM: xs @ [Win | Wc] -> l1 (relu, split, cols<512) + hc (fp32, cols>=512) ---
    k_gemm_mfma<<<dim3(768 / 64, NNODE / 128), 256, 0, stream>>>(
        xsh, xsl, 512, nullptr, nullptr, 0, wAt_h, wAt_l, 512,
        b_in_self, 1, l1h, l1l, 512, 512, hc, 256);

    // --- double aggregation: t1 = S hc ; g2 = S t1 + svec*bc + gb2 (split) ---
    k_agg2<0><<<NNODE, 256, 0, stream>>>(row_start, slist, wlist, dinv, hc,
                                         nullptr, nullptr, nullptr, t1, nullptr, nullptr);
    k_agg2<1><<<NNODE, 256, 0, stream>>>(row_start, slist, wlist, dinv, t1,
                                         svec, bc, gb2, nullptr, g2h, g2l);

    // --- z columns ---
    // z[:, :256] = [xs | l1] @ wost + b_out_self
    k_gemm_mfma<<<dim3(4, NNODE / 128), 256, 0, stream>>>(
        xsh, xsl, 512, l1h, l1l, 512, wost_h, wost_l, 1024,
        b_out_self, 0, zhi, zlo, 512, 256, nullptr, 0);
    // z[:, 256:] = [xn | g2] @ wot + b_out
    k_gemm_mfma<<<dim3(4, NNODE / 128), 256, 0, stream>>>(
        xnh, xnl, 512, g2h, g2l, 256, wot_h, wot_l, 768,
        b_out, 0, zhi + 256, zlo + 256, 512, 256, nullptr, 0);

    // --- out = sigmoid(z z^T) ---
    k_zzt_mfma<<<64 * 65 / 2, 256, 0, stream>>>(zhi, zlo, out);
}

// Round 5
// 414.623 us; speedup vs baseline: 2.5223x; 1.2546x over previous
//
#include <hip/hip_runtime.h>
#include <cstdint>
#include <cstddef>

#define NNODE 8192
#define NEDGE 262144

typedef __attribute__((ext_vector_type(8))) short bf16x8;
typedef __attribute__((ext_vector_type(4))) float f32x4;

// ---------------- bf16 split helpers ----------------
__device__ __forceinline__ unsigned short f2bf_rn(float x) {
    unsigned u = __float_as_uint(x);
    u = (u + 0x7FFFu + ((u >> 16) & 1u)) >> 16;
    return (unsigned short)u;
}
__device__ __forceinline__ float bf2f(unsigned short h) {
    return __uint_as_float(((unsigned)h) << 16);
}

// ---------------- CSR kernels ----------------

__global__ void k_zero_int(int* p, int n) {
    int i = blockIdx.x * blockDim.x + threadIdx.x;
    if (i < n) p[i] = 0;
}

__global__ void k_count(const int* __restrict__ dst, int* __restrict__ cnt, int n) {
    int i = blockIdx.x * blockDim.x + threadIdx.x;
    if (i < n) atomicAdd(&cnt[dst[i]], 1);
}

__global__ __launch_bounds__(256) void k_scan(const int* __restrict__ cnt,
                                              int* __restrict__ row_start,
                                              int* __restrict__ cursor,
                                              float* __restrict__ dinv) {
    __shared__ int part[256];
    const int tid = threadIdx.x;
    const int PER = NNODE / 256;  // 32
    const int base = tid * PER;
    int loc[PER];
    int sum = 0;
#pragma unroll
    for (int i = 0; i < PER; ++i) { loc[i] = cnt[base + i]; sum += loc[i]; }
    part[tid] = sum;
    __syncthreads();
    if (tid == 0) {
        int r = 0;
        for (int i = 0; i < 256; ++i) { int t = part[i]; part[i] = r; r += t; }
    }
    __syncthreads();
    int run = part[tid];
#pragma unroll
    for (int i = 0; i < PER; ++i) {
        row_start[base + i] = run;
        cursor[base + i] = run;
        dinv[base + i] = rsqrtf((float)loc[i] + 1.0f);  // deg = in-degree + self loop
        run += loc[i];
    }
    if (tid == 255) row_start[NNODE] = run;
}

__global__ void k_fill_csr2(const int* __restrict__ src, const int* __restrict__ dst,
                            int* __restrict__ cursor, const float* __restrict__ dinv,
                            int* __restrict__ slist, float* __restrict__ wlist, int n) {
    int e = blockIdx.x * blockDim.x + threadIdx.x;
    if (e < n) {
        int d = dst[e];
        int s = src[e];
        int pos = atomicAdd(&cursor[d], 1);
        slist[pos] = s;
        wlist[pos] = dinv[s] * dinv[d];
    }
}

// ---------------- mega prep kernel ----------------
// T0 [0,4096): split x_self -> xsh/xsl
// T1 [4096,8192): split x_neighbor -> xnh/xnl
// T2 [8192,8448): split_wt w_in_self (512,512) -> wAt rows 0..511
// T3 [8448,8576): Wc tile = gw1@gw2, split-transposed -> wAt rows 512..767
// T4 [8576,8832): split_wt w_out_self (1024,256) -> wost
// T5 [8832,9024): split_wt w_out (768,256) -> wot
// T6 [9024]: bc = gb1^T @ gw2
__device__ __forceinline__ void split_wt_tile(const float* __restrict__ W, int K, int N,
                                              int k0, int n0,
                                              unsigned short* __restrict__ Oh,
                                              unsigned short* __restrict__ Ol,
                                              float (*t)[33]) {
    const int c = threadIdx.x & 31, r8 = threadIdx.x >> 5;
#pragma unroll
    for (int i = 0; i < 4; ++i) {
        int r = r8 + i * 8;
        t[r][c] = W[(size_t)(k0 + r) * N + n0 + c];
    }
    __syncthreads();
#pragma unroll
    for (int i = 0; i < 4; ++i) {
        int r = r8 + i * 8;
        float x = t[c][r];
        unsigned short h = f2bf_rn(x);
        Oh[(size_t)(n0 + r) * K + k0 + c] = h;
        Ol[(size_t)(n0 + r) * K + k0 + c] = f2bf_rn(x - bf2f(h));
    }
}

__global__ __launch_bounds__(256) void k_prep(
    const float* __restrict__ x_self, const float* __restrict__ x_neighbor,
    const float* __restrict__ w_in_self, const float* __restrict__ w_out_self,
    const float* __restrict__ w_out, const float* __restrict__ gw1,
    const float* __restrict__ gw2, const float* __restrict__ gb1,
    unsigned short* __restrict__ xsh, unsigned short* __restrict__ xsl,
    unsigned short* __restrict__ xnh, unsigned short* __restrict__ xnl,
    unsigned short* __restrict__ wAt_h, unsigned short* __restrict__ wAt_l,
    unsigned short* __restrict__ wost_h, unsigned short* __restrict__ wost_l,
    unsigned short* __restrict__ wot_h, unsigned short* __restrict__ wot_l,
    float* __restrict__ bc) {
    __shared__ float t[32][33];
    const int b = blockIdx.x;
    const int tid = threadIdx.x;
    if (b < 8192) {  // T0/T1: splits
        const float* src = (b < 4096) ? x_self : x_neighbor;
        unsigned short* oh = (b < 4096) ? xsh : xnh;
        unsigned short* ol = (b < 4096) ? xsl : xnl;
        const int i = (b & 4095) * 256 + tid;
        float4 v = ((const float4*)src)[i];
        float x[4] = {v.x, v.y, v.z, v.w};
        unsigned short h[4], l[4];
#pragma unroll
        for (int j = 0; j < 4; ++j) {
            h[j] = f2bf_rn(x[j]);
            l[j] = f2bf_rn(x[j] - bf2f(h[j]));
        }
        ((ushort4*)oh)[i] = make_ushort4(h[0], h[1], h[2], h[3]);
        ((ushort4*)ol)[i] = make_ushort4(l[0], l[1], l[2], l[3]);
    } else if (b < 8448) {  // T2
        const int b2 = b - 8192;
        split_wt_tile(w_in_self, 512, 512, (b2 & 15) * 32, (b2 >> 4) * 32, wAt_h, wAt_l, t);
    } else if (b < 8576) {  // T3: Wc on the fly
        const int b3 = b - 8448;
        const int k0 = (b3 & 15) * 32, n0 = (b3 >> 4) * 32;
        const int nloc = tid & 31, kg = tid >> 5;  // kg 0..7 -> rows kg*4..+3
        float a[4] = {0.f, 0.f, 0.f, 0.f};
        for (int c = 0; c < 512; ++c) {
            float g2v = gw2[(size_t)c * 256 + n0 + nloc];
#pragma unroll
            for (int i = 0; i < 4; ++i)
                a[i] += gw1[(size_t)(k0 + kg * 4 + i) * 512 + c] * g2v;
        }
#pragma unroll
        for (int i = 0; i < 4; ++i) {
            unsigned short hh = f2bf_rn(a[i]);
            wAt_h[(size_t)(512 + n0 + nloc) * 512 + k0 + kg * 4 + i] = hh;
            wAt_l[(size_t)(512 + n0 + nloc) * 512 + k0 + kg * 4 + i] = f2bf_rn(a[i] - bf2f(hh));
        }
    } else if (b < 8832) {  // T4
        const int b4 = b - 8576;
        split_wt_tile(w_out_self, 1024, 256, (b4 & 31) * 32, (b4 >> 5) * 32, wost_h, wost_l, t);
    } else if (b < 9024) {  // T5
        const int b5 = b - 8832;
        split_wt_tile(w_out, 768, 256, (b5 % 24) * 32, (b5 / 24) * 32, wot_h, wot_l, t);
    } else {  // T6: bc
        float a = 0.0f;
        for (int c = 0; c < 512; ++c) a += gb1[c] * gw2[(size_t)c * 256 + tid];
        bc[tid] = a;
    }
}

// ---------------- split-bf16 MFMA GEMM, BM=128 BN=64 BK=32, 4 waves ----------------
// swizzle: LDS slot (row rho, s) holds k-chunk s ^ ((rho>>1)&3); 2 lanes/bank on read.
__global__ __launch_bounds__(256) void k_gemm_mfma(
    const unsigned short* __restrict__ A1h, const unsigned short* __restrict__ A1l, int K1,
    const unsigned short* __restrict__ Wth, const unsigned short* __restrict__ Wtl, int Ktot,
    const float* __restrict__ bias1, int relu1,
    unsigned short* __restrict__ C1h, unsigned short* __restrict__ C1l, int ldc1, int N1,
    float* __restrict__ C2f, int ldc2) {
    __shared__ __align__(16) char smem[24576];  // Ah | Al | Bh | Bl
    const int tid = threadIdx.x;
    const int lane = tid & 63;
    const int w = tid >> 6;
    const int bm = blockIdx.y * 128;
    const int bn = blockIdx.x * 64;
    const int crow = lane >> 2;
    const int swz_src = ((lane & 3) ^ ((lane >> 3) & 3)) * 16;
    const int sread = ((lane >> 4) ^ ((lane >> 1) & 3)) * 16;
    const size_t wrowb = (size_t)Ktot * 2;
    const size_t arowb = (size_t)K1 * 2;

    f32x4 acc[2][4] = {};

    for (int k0 = 0; k0 < Ktot; k0 += 32) {
        const int kb = k0 * 2;
#pragma unroll
        for (int i = 0; i < 6; ++i) {
            const int k = w * 6 + i;  // chunk 0..23
            char* lp = smem + k * 1024;
            const char* gp;
            if (k < 8) {
                gp = (const char*)A1h + (size_t)(bm + k * 16 + crow) * arowb + kb + swz_src;
            } else if (k < 16) {
                gp = (const char*)A1l + (size_t)(bm + (k - 8) * 16 + crow) * arowb + kb + swz_src;
            } else if (k < 20) {
                gp = (const char*)Wth + (size_t)(bn + (k - 16) * 16 + crow) * wrowb + kb + swz_src;
            } else {
                gp = (const char*)Wtl + (size_t)(bn + (k - 20) * 16 + crow) * wrowb + kb + swz_src;
            }
            __builtin_amdgcn_global_load_lds((const __attribute__((address_space(1))) void*)gp,
                                             (__attribute__((address_space(3))) void*)lp, 16, 0, 0);
        }
        __syncthreads();

        bf16x8 ah[2], al[2], bh[4], bl[4];
#pragma unroll
        for (int m = 0; m < 2; ++m) {
            const int row = w * 32 + m * 16 + (lane & 15);
            ah[m] = *(const bf16x8*)(smem + row * 64 + sread);
            al[m] = *(const bf16x8*)(smem + 8192 + row * 64 + sread);
        }
#pragma unroll
        for (int n = 0; n < 4; ++n) {
            const int row = n * 16 + (lane & 15);
            bh[n] = *(const bf16x8*)(smem + 16384 + row * 64 + sread);
            bl[n] = *(const bf16x8*)(smem + 20480 + row * 64 + sread);
        }
#pragma unroll
        for (int m = 0; m < 2; ++m)
#pragma unroll
            for (int n = 0; n < 4; ++n) {
                acc[m][n] = __builtin_amdgcn_mfma_f32_16x16x32_bf16(ah[m], bh[n], acc[m][n], 0, 0, 0);
                acc[m][n] = __builtin_amdgcn_mfma_f32_16x16x32_bf16(ah[m], bl[n], acc[m][n], 0, 0, 0);
                acc[m][n] = __builtin_amdgcn_mfma_f32_16x16x32_bf16(al[m], bh[n], acc[m][n], 0, 0, 0);
            }
        __syncthreads();
    }

    const int rj = (lane >> 4) * 4;
    const int cc = lane & 15;
#pragma unroll
    for (int m = 0; m < 2; ++m) {
#pragma unroll
        for (int n = 0; n < 4; ++n) {
            const int col = bn + n * 16 + cc;
#pragma unroll
            for (int j = 0; j < 4; ++j) {
                const int row = bm + w * 32 + m * 16 + rj + j;
                float x = acc[m][n][j];
                if (col < N1) {
                    if (bias1) x += bias1[col];
                    if (relu1) x = fmaxf(x, 0.0f);
                    unsigned short h = f2bf_rn(x);
                    C1h[(size_t)row * ldc1 + col] = h;
                    C1l[(size_t)row * ldc1 + col] = f2bf_rn(x - bf2f(h));
                } else {
                    C2f[(size_t)row * ldc2 + (col - N1)] = x;
                }
            }
        }
    }
}

// ---------------- fused z1+z2 GEMM (same structure, param switch per block) ----------------
__global__ __launch_bounds__(256) void k_gemm_z(
    const unsigned short* __restrict__ xsh, const unsigned short* __restrict__ xsl,
    const unsigned short* __restrict__ l1h, const unsigned short* __restrict__ l1l,
    const unsigned short* __restrict__ xnh, const unsigned short* __restrict__ xnl,
    const unsigned short* __restrict__ g2h, const unsigned short* __restrict__ g2l,
    const unsigned short* __restrict__ wost_h, const unsigned short* __restrict__ wost_l,
    const unsigned short* __restrict__ wot_h, const unsigned short* __restrict__ wot_l,
    const float* __restrict__ b_out_self, const float* __restrict__ b_out,
    unsigned short* __restrict__ zhi, unsigned short* __restrict__ zlo) {
    __shared__ __align__(16) char smem[24576];
    const unsigned short *A1h, *A1l, *A2h, *A2l, *Wh, *Wl;
    const float* bias;
    int K1, K2, Ktot, zoff;
    if (blockIdx.x < 4) {
        A1h = xsh; A1l = xsl; K1 = 512; A2h = l1h; A2l = l1l; K2 = 512;
        Wh = wost_h; Wl = wost_l; Ktot = 1024; bias = b_out_self; zoff = 0;
    } else {
        A1h = xnh; A1l = xnl; K1 = 512; A2h = g2h; A2l = g2l; K2 = 256;
        Wh = wot_h; Wl = wot_l; Ktot = 768; bias = b_out; zoff = 256;
    }
    const int tid = threadIdx.x;
    const int lane = tid & 63;
    const int w = tid >> 6;
    const int bm = blockIdx.y * 128;
    const int bn = (blockIdx.x & 3) * 64;
    const int crow = lane >> 2;
    const int swz_src = ((lane & 3) ^ ((lane >> 3) & 3)) * 16;
    const int sread = ((lane >> 4) ^ ((lane >> 1) & 3)) * 16;
    const size_t wrowb = (size_t)Ktot * 2;

    f32x4 acc[2][4] = {};

    for (int k0 = 0; k0 < Ktot; k0 += 32) {
        const char *Ah, *Al;
        size_t rowbA;
        int kbA;
        if (k0 < K1) { Ah = (const char*)A1h; Al = (const char*)A1l; rowbA = (size_t)K1 * 2; kbA = k0 * 2; }
        else         { Ah = (const char*)A2h; Al = (const char*)A2l; rowbA = (size_t)K2 * 2; kbA = (k0 - K1) * 2; }
        const int kbW = k0 * 2;
#pragma unroll
        for (int i = 0; i < 6; ++i) {
            const int k = w * 6 + i;
            char* lp = smem + k * 1024;
            const char* gp;
            if (k < 8) {
                gp = Ah + (size_t)(bm + k * 16 + crow) * rowbA + kbA + swz_src;
            } else if (k < 16) {
                gp = Al + (size_t)(bm + (k - 8) * 16 + crow) * rowbA + kbA + swz_src;
            } else if (k < 20) {
                gp = (const char*)Wh + (size_t)(bn + (k - 16) * 16 + crow) * wrowb + kbW + swz_src;
            } else {
                gp = (const char*)Wl + (size_t)(bn + (k - 20) * 16 + crow) * wrowb + kbW + swz_src;
            }
            __builtin_amdgcn_global_load_lds((const __attribute__((address_space(1))) void*)gp,
                                             (__attribute__((address_space(3))) void*)lp, 16, 0, 0);
        }
        __syncthreads();

        bf16x8 ah[2], al[2], bh[4], bl[4];
#pragma unroll
        for (int m = 0; m < 2; ++m) {
            const int row = w * 32 + m * 16 + (lane & 15);
            ah[m] = *(const bf16x8*)(smem + row * 64 + sread);
            al[m] = *(const bf16x8*)(smem + 8192 + row * 64 + sread);
        }
#pragma unroll
        for (int n = 0; n < 4; ++n) {
            const int row = n * 16 + (lane & 15);
            bh[n] = *(const bf16x8*)(smem + 16384 + row * 64 + sread);
            bl[n] = *(const bf16x8*)(smem + 20480 + row * 64 + sread);
        }
#pragma unroll
        for (int m = 0; m < 2; ++m)
#pragma unroll
            for (int n = 0; n < 4; ++n) {
                acc[m][n] = __builtin_amdgcn_mfma_f32_16x16x32_bf16(ah[m], bh[n], acc[m][n], 0, 0, 0);
                acc[m][n] = __builtin_amdgcn_mfma_f32_16x16x32_bf16(ah[m], bl[n], acc[m][n], 0, 0, 0);
                acc[m][n] = __builtin_amdgcn_mfma_f32_16x16x32_bf16(al[m], bh[n], acc[m][n], 0, 0, 0);
            }
        __syncthreads();
    }

    const int rj = (lane >> 4) * 4;
    const int cc = lane & 15;
#pragma unroll
    for (int m = 0; m < 2; ++m) {
#pragma unroll
        for (int n = 0; n < 4; ++n) {
            const int col = bn + n * 16 + cc;  // 0..255 within this z half
            const float bv = bias[col];
#pragma unroll
            for (int j = 0; j < 4; ++j) {
                const int row = bm + w * 32 + m * 16 + rj + j;
                float x = acc[m][n][j] + bv;
                unsigned short h = f2bf_rn(x);
                zhi[(size_t)row * 512 + zoff + col] = h;
                zlo[(size_t)row * 512 + zoff + col] = f2bf_rn(x - bf2f(h));
            }
        }
    }
}

// ---------------- GCN aggregation, unrolled gathers ----------------
// MODE 0: outf = S_hat @ h (fp32); MODE 1: split-bf16( S_hat @ h + svec*bc + b2 )
template <int MODE>
__global__ __launch_bounds__(256) void k_agg2(
    const int* __restrict__ row_start, const int* __restrict__ slist,
    const float* __restrict__ wlist, const float* __restrict__ dinv,
    const float* __restrict__ h,
    const float* __restrict__ bc, const float* __restrict__ b2,
    float* __restrict__ outf,
    unsigned short* __restrict__ oh, unsigned short* __restrict__ ol) {
    const int n = blockIdx.x;
    const int c = threadIdx.x;
    const float di = dinv[n];
    float acc = di * di * h[(size_t)n * 256 + c];
    float sv = di * di;
    const int e0 = row_start[n], e1 = row_start[n + 1];
    int j = e0;
    for (; j + 4 <= e1; j += 4) {
        const int s0 = slist[j], s1 = slist[j + 1], s2 = slist[j + 2], s3 = slist[j + 3];
        const float w0 = wlist[j], w1 = wlist[j + 1], w2 = wlist[j + 2], w3 = wlist[j + 3];
        const float v0 = h[(size_t)s0 * 256 + c];
        const float v1 = h[(size_t)s1 * 256 + c];
        const float v2 = h[(size_t)s2 * 256 + c];
        const float v3 = h[(size_t)s3 * 256 + c];
        acc += w0 * v0; acc += w1 * v1; acc += w2 * v2; acc += w3 * v3;
        if (MODE) sv += w0 + w1 + w2 + w3;
    }
    for (; j < e1; ++j) {
        const float wv = wlist[j];
        acc += wv * h[(size_t)slist[j] * 256 + c];
        if (MODE) sv += wv;
    }
    if (MODE == 0) {
        outf[(size_t)n * 256 + c] = acc;
    } else {
        float x = acc + sv * bc[c] + b2[c];
        unsigned short hb = f2bf_rn(x);
        oh[(size_t)n * 256 + c] = hb;
        ol[(size_t)n * 256 + c] = f2bf_rn(x - bf2f(hb));
    }
}

// ---------------- out = sigmoid(Z Z^T), 2-phase double-buffered prefetch ----------------
__device__ __forceinline__ void zzt_stage(char* buf, const char* s0, const char* s1,
                                          const char* s2, const char* s3,
                                          int rloc, int swz_src, int w, int kbyte) {
    const char* srcs[4] = {s0, s1, s2, s3};
#pragma unroll
    for (int tile = 0; tile < 4; ++tile) {
#pragma unroll
        for (int i = 0; i < 2; ++i) {
            const char* gp = srcs[tile] + (size_t)(rloc + i * 64) * 1024 + kbyte + swz_src;
            char* lp = buf + tile * 8192 + i * 4096 + w * 1024;
            __builtin_amdgcn_global_load_lds(
                (const __attribute__((address_space(1))) void*)gp,
                (__attribute__((address_space(3))) void*)lp, 16, 0, 0);
        }
    }
}

__global__ __launch_bounds__(256) void k_zzt_mfma(const unsigned short* __restrict__ zhi,
                                                  const unsigned short* __restrict__ zlo,
                                                  float* __restrict__ out) {
    __shared__ __align__(16) char smem[65536];  // 2 x 32KB
    const int tid = threadIdx.x;
    const int lane = tid & 63;
    const int w = tid >> 6;
    const int wr = w >> 1, wc = w & 1;

    const int t = blockIdx.x;
    int bi = (int)((sqrtf(8.0f * (float)t + 1.0f) - 1.0f) * 0.5f);
    while ((bi + 1) * (bi + 2) / 2 <= t) ++bi;
    while (bi * (bi + 1) / 2 > t) --bi;
    const int bj = t - bi * (bi + 1) / 2;

    const char* s0 = (const char*)zhi + (size_t)(bi * 128) * 1024;
    const char* s1 = (const char*)zlo + (size_t)(bi * 128) * 1024;
    const char* s2 = (const char*)zhi + (size_t)(bj * 128) * 1024;
    const char* s3 = (const char*)zlo + (size_t)(bj * 128) * 1024;

    const int rloc = w * 16 + (lane >> 2);
    const int swz_src = ((lane & 3) ^ ((lane >> 3) & 3)) * 16;
    const int sread = ((lane >> 4) ^ ((lane >> 1) & 3)) * 16;

    f32x4 acc[4][4] = {};

    zzt_stage(smem, s0, s1, s2, s3, rloc, swz_src, w, 0);
    __syncthreads();

    for (int ks = 0; ks < 16; ++ks) {
        char* cur = smem + (ks & 1) * 32768;
        if (ks < 15)
            zzt_stage(smem + ((ks + 1) & 1) * 32768, s0, s1, s2, s3, rloc, swz_src, w,
                      (ks + 1) * 64);

        bf16x8 ah[4], al[4], bh[4], bl[4];
        const char* pa = cur + (wr * 64 + (lane & 15)) * 64 + sread;
        const char* pb = cur + 16384 + (wc * 64 + (lane & 15)) * 64 + sread;
#pragma unroll
        for (int m = 0; m < 4; ++m) {
            ah[m] = *(const bf16x8*)(pa + m * 1024);
            al[m] = *(const bf16x8*)(pa + 8192 + m * 1024);
        }
#pragma unroll
        for (int n = 0; n < 4; ++n) {
            bh[n] = *(const bf16x8*)(pb + n * 1024);
            bl[n] = *(const bf16x8*)(pb + 8192 + n * 1024);
        }
#pragma unroll
        for (int m = 0; m < 4; ++m)
#pragma unroll
            for (int n = 0; n < 4; ++n) {
                acc[m][n] = __builtin_amdgcn_mfma_f32_16x16x32_bf16(ah[m], bh[n], acc[m][n], 0, 0, 0);
                acc[m][n] = __builtin_amdgcn_mfma_f32_16x16x32_bf16(ah[m], bl[n], acc[m][n], 0, 0, 0);
                acc[m][n] = __builtin_amdgcn_mfma_f32_16x16x32_bf16(al[m], bh[n], acc[m][n], 0, 0, 0);
            }
        __syncthreads();  // drains vmcnt(0)+lgkmcnt(0): prefetch landed, reads done
    }

    const int rj = (lane >> 4) * 4;
    const int cc = lane & 15;
#pragma unroll
    for (int m = 0; m < 4; ++m) {
#pragma unroll
        for (int n = 0; n < 4; ++n) {
            float s[4];
#pragma unroll
            for (int j = 0; j < 4; ++j)
                s[j] = 1.0f / (1.0f + __expf(-acc[m][n][j]));
            const int gr0 = bi * 128 + wr * 64 + m * 16 + rj;
            const int gc  = bj * 128 + wc * 64 + n * 16 + cc;
#pragma unroll
            for (int j = 0; j < 4; ++j)
                out[(size_t)(gr0 + j) * NNODE + gc] = s[j];
            if (bi != bj) {
                const int mr = bj * 128 + wc * 64 + n * 16 + cc;
                const int mc = bi * 128 + wr * 64 + m * 16 + rj;
                *(float4*)(out + (size_t)mr * NNODE + mc) = make_float4(s[0], s[1], s[2], s[3]);
            }
        }
    }
}

// ---------------- launch ----------------
extern "C" void kernel_launch(void* const* d_in, const int* in_sizes, int n_in,
                              void* d_out, int out_size, void* d_ws, size_t ws_size,
                              hipStream_t stream) {
    const float* x_self     = (const float*)d_in[0];
    const float* x_neighbor = (const float*)d_in[1];
    const int*   ei         = (const int*)d_in[2];
    const float* w_in_self  = (const float*)d_in[3];
    const float* b_in_self  = (const float*)d_in[4];
    const float* w_out_self = (const float*)d_in[5];
    const float* b_out_self = (const float*)d_in[6];
    const float* gw1        = (const float*)d_in[7];
    const float* gb1        = (const float*)d_in[8];
    const float* gw2        = (const float*)d_in[9];
    const float* gb2        = (const float*)d_in[10];
    const float* w_out      = (const float*)d_in[11];
    const float* b_out      = (const float*)d_in[12];
    float* out = (float*)d_out;

    char* ws = (char*)d_ws;
    const size_t MB = 1024 * 1024;
    const size_t KB = 1024;
    int*   cnt       = (int*)(ws + 0);
    int*   row_start = (int*)(ws + 32 * KB);
    int*   cursor    = (int*)(ws + 96 * KB);
    float* dinv      = (float*)(ws + 128 * KB);
    float* bc        = (float*)(ws + 192 * KB);
    int*   slist     = (int*)(ws + 2 * MB);
    float* wlist     = (float*)(ws + 3 * MB);
    unsigned short* xsh = (unsigned short*)(ws + 4 * MB);
    unsigned short* xsl = (unsigned short*)(ws + 12 * MB);
    unsigned short* xnh = (unsigned short*)(ws + 20 * MB);
    unsigned short* xnl = (unsigned short*)(ws + 28 * MB);
    unsigned short* l1h = (unsigned short*)(ws + 36 * MB);
    unsigned short* l1l = (unsigned short*)(ws + 44 * MB);
    float*          hc  = (float*)(ws + 52 * MB);   // 8 MB fp32 [8192,256]
    float*          t1  = (float*)(ws + 60 * MB);   // 8 MB fp32
    unsigned short* g2h = (unsigned short*)(ws + 68 * MB);
    unsigned short* g2l = (unsigned short*)(ws + 72 * MB);
    unsigned short* zhi = (unsigned short*)(ws + 76 * MB);
    unsigned short* zlo = (unsigned short*)(ws + 84 * MB);
    unsigned short* wAt_h = (unsigned short*)(ws + 92 * MB);   // [768,512]
    unsigned short* wAt_l = (unsigned short*)(ws + 93 * MB);
    unsigned short* wost_h = (unsigned short*)(ws + 94 * MB);  // [256,1024]
    unsigned short* wost_l = (unsigned short*)(ws + 95 * MB);
    unsigned short* wot_h  = (unsigned short*)(ws + 96 * MB);  // [256,768]
    unsigned short* wot_l  = (unsigned short*)(ws + 97 * MB);

    const int* srcA = ei;          // edge_index[0]
    const int* dstA = ei + NEDGE;  // edge_index[1]

    // prep (splits + all weight transforms), independent of CSR
    k_prep<<<9025, 256, 0, stream>>>(x_self, x_neighbor, w_in_self, w_out_self, w_out,
                                     gw1, gw2, gb1, xsh, xsl, xnh, xnl,
                                     wAt_h, wAt_l, wost_h, wost_l, wot_h, wot_l, bc);

    // CSR build
    k_zero_int<<<NNODE / 256, 256, 0, stream>>>(cnt, NNODE);
    k_count<<<NEDGE / 256, 256, 0, stream>>>(dstA, cnt, NEDGE);
    k_scan<<<1, 256, 0, stream>>>(cnt, row_start, cursor, dinv);
    k_fill_csr2<<<NEDGE / 256, 256, 0, stream>>>(srcA, dstA, cursor, dinv, slist, wlist, NEDGE);

    // fused GEMM: xs @ [Win | Wc] -> l1 (relu, split, cols<512) + hc (fp32, cols>=512)
    k_gemm_mfma<<<dim3(768 / 64, NNODE / 128), 256, 0, stream>>>(
        xsh, xsl, 512, wAt_h, wAt_l, 512,
        b_in_self, 1, l1h, l1l, 512, 512, hc, 256);

    // double aggregation: t1 = S hc ; g2 = S t1 + svec*bc + gb2 (split, svec inline)
    k_agg2<0><<<NNODE, 256, 0, stream>>>(row_start, slist, wlist, dinv, hc,
                                         nullptr, nullptr, t1, nullptr, nullptr);
    k_agg2<1><<<NNODE, 256, 0, stream>>>(row_start, slist, wlist, dinv, t1,
                                         bc, gb2, nullptr, g2h, g2l);

    // z = [ [xs|l1]@wost + b_os , [xn|g2]@wot + b_o ]  (split into zhi/zlo)
    k_gemm_z<<<dim3(8, NNODE / 128), 256, 0, stream>>>(
        xsh, xsl, l1h, l1l, xnh, xnl, g2h, g2l,
        wost_h, wost_l, wot_h, wot_l, b_out_self, b_out, zhi, zlo);

    // out = sigmoid(z z^T)
    k_zzt_mfma<<<64 * 65 / 2, 256, 0, stream>>>(zhi, zlo, out);
}

// Round 6
// 389.993 us; speedup vs baseline: 2.6816x; 1.0632x over previous
//
#include <hip/hip_runtime.h>
#include <cstdint>
#include <cstddef>

#define NNODE 8192
#define NEDGE 262144

typedef __attribute__((ext_vector_type(8))) short bf16x8;
typedef __attribute__((ext_vector_type(4))) float f32x4;

// ---------------- bf16 split helpers ----------------
__device__ __forceinline__ unsigned short f2bf_rn(float x) {
    unsigned u = __float_as_uint(x);
    u = (u + 0x7FFFu + ((u >> 16) & 1u)) >> 16;
    return (unsigned short)u;
}
__device__ __forceinline__ float bf2f(unsigned short h) {
    return __uint_as_float(((unsigned)h) << 16);
}

__device__ __forceinline__ void gload16(const char* gp, char* lp) {
    __builtin_amdgcn_global_load_lds((const __attribute__((address_space(1))) void*)gp,
                                     (__attribute__((address_space(3))) void*)lp, 16, 0, 0);
}

// ---------------- CSR kernels ----------------

__global__ void k_zero_int(int* p, int n) {
    int i = blockIdx.x * blockDim.x + threadIdx.x;
    if (i < n) p[i] = 0;
}

__global__ void k_count(const int* __restrict__ dst, int* __restrict__ cnt, int n) {
    int i = blockIdx.x * blockDim.x + threadIdx.x;
    if (i < n) atomicAdd(&cnt[dst[i]], 1);
}

__global__ __launch_bounds__(256) void k_scan(const int* __restrict__ cnt,
                                              int* __restrict__ row_start,
                                              int* __restrict__ cursor,
                                              float* __restrict__ dinv) {
    __shared__ int part[256];
    const int tid = threadIdx.x;
    const int PER = NNODE / 256;  // 32
    const int base = tid * PER;
    int loc[PER];
    int sum = 0;
#pragma unroll
    for (int i = 0; i < PER; ++i) { loc[i] = cnt[base + i]; sum += loc[i]; }
    part[tid] = sum;
    __syncthreads();
    if (tid == 0) {
        int r = 0;
        for (int i = 0; i < 256; ++i) { int t = part[i]; part[i] = r; r += t; }
    }
    __syncthreads();
    int run = part[tid];
#pragma unroll
    for (int i = 0; i < PER; ++i) {
        row_start[base + i] = run;
        cursor[base + i] = run;
        dinv[base + i] = rsqrtf((float)loc[i] + 1.0f);  // deg = in-degree + self loop
        run += loc[i];
    }
    if (tid == 255) row_start[NNODE] = run;
}

__global__ void k_fill_csr2(const int* __restrict__ src, const int* __restrict__ dst,
                            int* __restrict__ cursor, const float* __restrict__ dinv,
                            int* __restrict__ slist, float* __restrict__ wlist, int n) {
    int e = blockIdx.x * blockDim.x + threadIdx.x;
    if (e < n) {
        int d = dst[e];
        int s = src[e];
        int pos = atomicAdd(&cursor[d], 1);
        slist[pos] = s;
        wlist[pos] = dinv[s] * dinv[d];
    }
}

// ---------------- mega prep kernel ----------------
__device__ __forceinline__ void split_wt_tile(const float* __restrict__ W, int K, int N,
                                              int k0, int n0,
                                              unsigned short* __restrict__ Oh,
                                              unsigned short* __restrict__ Ol,
                                              float (*t)[33]) {
    const int c = threadIdx.x & 31, r8 = threadIdx.x >> 5;
#pragma unroll
    for (int i = 0; i < 4; ++i) {
        int r = r8 + i * 8;
        t[r][c] = W[(size_t)(k0 + r) * N + n0 + c];
    }
    __syncthreads();
#pragma unroll
    for (int i = 0; i < 4; ++i) {
        int r = r8 + i * 8;
        float x = t[c][r];
        unsigned short h = f2bf_rn(x);
        Oh[(size_t)(n0 + r) * K + k0 + c] = h;
        Ol[(size_t)(n0 + r) * K + k0 + c] = f2bf_rn(x - bf2f(h));
    }
}

__global__ __launch_bounds__(256) void k_prep(
    const float* __restrict__ x_self, const float* __restrict__ x_neighbor,
    const float* __restrict__ w_in_self, const float* __restrict__ w_out_self,
    const float* __restrict__ w_out, const float* __restrict__ gw1,
    const float* __restrict__ gw2, const float* __restrict__ gb1,
    unsigned short* __restrict__ xsh, unsigned short* __restrict__ xsl,
    unsigned short* __restrict__ xnh, unsigned short* __restrict__ xnl,
    unsigned short* __restrict__ wAt_h, unsigned short* __restrict__ wAt_l,
    unsigned short* __restrict__ wost_h, unsigned short* __restrict__ wost_l,
    unsigned short* __restrict__ wot_h, unsigned short* __restrict__ wot_l,
    float* __restrict__ bc) {
    __shared__ float t[32][33];
    const int b = blockIdx.x;
    const int tid = threadIdx.x;
    if (b < 8192) {  // splits
        const float* src = (b < 4096) ? x_self : x_neighbor;
        unsigned short* oh = (b < 4096) ? xsh : xnh;
        unsigned short* ol = (b < 4096) ? xsl : xnl;
        const int i = (b & 4095) * 256 + tid;
        float4 v = ((const float4*)src)[i];
        float x[4] = {v.x, v.y, v.z, v.w};
        unsigned short h[4], l[4];
#pragma unroll
        for (int j = 0; j < 4; ++j) {
            h[j] = f2bf_rn(x[j]);
            l[j] = f2bf_rn(x[j] - bf2f(h[j]));
        }
        ((ushort4*)oh)[i] = make_ushort4(h[0], h[1], h[2], h[3]);
        ((ushort4*)ol)[i] = make_ushort4(l[0], l[1], l[2], l[3]);
    } else if (b < 8448) {
        const int b2 = b - 8192;
        split_wt_tile(w_in_self, 512, 512, (b2 & 15) * 32, (b2 >> 4) * 32, wAt_h, wAt_l, t);
    } else if (b < 8576) {  // Wc = gw1 @ gw2 on the fly
        const int b3 = b - 8448;
        const int k0 = (b3 & 15) * 32, n0 = (b3 >> 4) * 32;
        const int nloc = tid & 31, kg = tid >> 5;
        float a[4] = {0.f, 0.f, 0.f, 0.f};
        for (int c = 0; c < 512; ++c) {
            float g2v = gw2[(size_t)c * 256 + n0 + nloc];
#pragma unroll
            for (int i = 0; i < 4; ++i)
                a[i] += gw1[(size_t)(k0 + kg * 4 + i) * 512 + c] * g2v;
        }
#pragma unroll
        for (int i = 0; i < 4; ++i) {
            unsigned short hh = f2bf_rn(a[i]);
            wAt_h[(size_t)(512 + n0 + nloc) * 512 + k0 + kg * 4 + i] = hh;
            wAt_l[(size_t)(512 + n0 + nloc) * 512 + k0 + kg * 4 + i] = f2bf_rn(a[i] - bf2f(hh));
        }
    } else if (b < 8832) {
        const int b4 = b - 8576;
        split_wt_tile(w_out_self, 1024, 256, (b4 & 31) * 32, (b4 >> 5) * 32, wost_h, wost_l, t);
    } else if (b < 9024) {
        const int b5 = b - 8832;
        split_wt_tile(w_out, 768, 256, (b5 % 24) * 32, (b5 / 24) * 32, wot_h, wot_l, t);
    } else {
        float a = 0.0f;
        for (int c = 0; c < 512; ++c) a += gb1[c] * gw2[(size_t)c * 256 + tid];
        bc[tid] = a;
    }
}

// ---------------- shared GEMM pieces (128x64 tile, 4 waves, BK=32) ----------------
// LDS buffer (24 KB): Ah[128][64B]@0 | Al@8192 | Bh[64][64B]@16384 | Bl@20480
// stage: sources pre-offset with bm/bn*stride + kbyte + swz_src.
__device__ __forceinline__ void stage_g(char* buf,
                                        const char* aH, const char* aL, size_t strA,
                                        const char* bH, const char* bL, size_t strB,
                                        int rloc, int w) {
#pragma unroll
    for (int i = 0; i < 2; ++i) {
        const size_t r = (size_t)(rloc + i * 64);
        char* lp = buf + i * 4096 + w * 1024;
        gload16(aH + r * strA, lp);
        gload16(aL + r * strA, lp + 8192);
    }
    gload16(bH + (size_t)rloc * strB, buf + 16384 + w * 1024);
    gload16(bL + (size_t)rloc * strB, buf + 20480 + w * 1024);
}

__device__ __forceinline__ void core_2x4(const char* cur, int w, int sread, int lane,
                                         f32x4 acc[2][4]) {
    bf16x8 ah[2], al[2], bh[4], bl[4];
#pragma unroll
    for (int m = 0; m < 2; ++m) {
        const int row = w * 32 + m * 16 + (lane & 15);
        ah[m] = *(const bf16x8*)(cur + row * 64 + sread);
        al[m] = *(const bf16x8*)(cur + 8192 + row * 64 + sread);
    }
#pragma unroll
    for (int n = 0; n < 4; ++n) {
        const int row = n * 16 + (lane & 15);
        bh[n] = *(const bf16x8*)(cur + 16384 + row * 64 + sread);
        bl[n] = *(const bf16x8*)(cur + 20480 + row * 64 + sread);
    }
#pragma unroll
    for (int m = 0; m < 2; ++m)
#pragma unroll
        for (int n = 0; n < 4; ++n) {
            acc[m][n] = __builtin_amdgcn_mfma_f32_16x16x32_bf16(ah[m], bh[n], acc[m][n], 0, 0, 0);
            acc[m][n] = __builtin_amdgcn_mfma_f32_16x16x32_bf16(ah[m], bl[n], acc[m][n], 0, 0, 0);
            acc[m][n] = __builtin_amdgcn_mfma_f32_16x16x32_bf16(al[m], bh[n], acc[m][n], 0, 0, 0);
        }
}

// ---------------- GEMM-A: xs @ [Win | Wc] -> l1 (relu,split) + hc (fp32) ----------------
// BM=128 BN=64, 2-phase dbuf. grid (12, 64). K=512.
__global__ __launch_bounds__(256) void k_gemm128_A(
    const unsigned short* __restrict__ xsh, const unsigned short* __restrict__ xsl,
    const unsigned short* __restrict__ wAt_h, const unsigned short* __restrict__ wAt_l,
    const float* __restrict__ bias,
    unsigned short* __restrict__ l1h, unsigned short* __restrict__ l1l,
    float* __restrict__ hc) {
    __shared__ __align__(16) char smem[49152];
    const int tid = threadIdx.x, lane = tid & 63, w = tid >> 6;
    const int bm = blockIdx.y * 128, bn = blockIdx.x * 64;
    const int rloc = w * 16 + (lane >> 2);
    const int swz_src = ((lane & 3) ^ ((lane >> 3) & 3)) * 16;
    const int sread = ((lane >> 4) ^ ((lane >> 1) & 3)) * 16;
    const char* Ah = (const char*)xsh + (size_t)bm * 1024 + swz_src;
    const char* Al = (const char*)xsl + (size_t)bm * 1024 + swz_src;
    const char* Bh = (const char*)wAt_h + (size_t)bn * 1024 + swz_src;
    const char* Bl = (const char*)wAt_l + (size_t)bn * 1024 + swz_src;

    f32x4 acc[2][4] = {};
    stage_g(smem, Ah, Al, 1024, Bh, Bl, 1024, rloc, w);
    __syncthreads();
    for (int ks = 0; ks < 16; ++ks) {
        char* cur = smem + (ks & 1) * 24576;
        if (ks < 15) {
            const int kb = (ks + 1) * 64;
            stage_g(smem + ((ks + 1) & 1) * 24576, Ah + kb, Al + kb, 1024,
                    Bh + kb, Bl + kb, 1024, rloc, w);
        }
        core_2x4(cur, w, sread, lane, acc);
        __syncthreads();
    }

    const int rj = (lane >> 4) * 4, cc = lane & 15;
#pragma unroll
    for (int m = 0; m < 2; ++m) {
#pragma unroll
        for (int n = 0; n < 4; ++n) {
            const int col = bn + n * 16 + cc;
#pragma unroll
            for (int j = 0; j < 4; ++j) {
                const int row = bm + w * 32 + m * 16 + rj + j;
                float x = acc[m][n][j];
                if (col < 512) {
                    x += bias[col];
                    x = fmaxf(x, 0.0f);
                    unsigned short h = f2bf_rn(x);
                    l1h[(size_t)row * 512 + col] = h;
                    l1l[(size_t)row * 512 + col] = f2bf_rn(x - bf2f(h));
                } else {
                    hc[(size_t)row * 256 + (col - 512)] = x;
                }
            }
        }
    }
}

// ---------------- GEMM-Z: z halves, concat-K, 2-phase dbuf. grid (8, 64) ----------------
__global__ __launch_bounds__(256) void k_gemm128_Z(
    const unsigned short* __restrict__ xsh, const unsigned short* __restrict__ xsl,
    const unsigned short* __restrict__ l1h, const unsigned short* __restrict__ l1l,
    const unsigned short* __restrict__ xnh, const unsigned short* __restrict__ xnl,
    const unsigned short* __restrict__ g2h, const unsigned short* __restrict__ g2l,
    const unsigned short* __restrict__ wost_h, const unsigned short* __restrict__ wost_l,
    const unsigned short* __restrict__ wot_h, const unsigned short* __restrict__ wot_l,
    const float* __restrict__ b_out_self, const float* __restrict__ b_out,
    unsigned short* __restrict__ zhi, unsigned short* __restrict__ zlo) {
    __shared__ __align__(16) char smem[49152];
    const int half = blockIdx.x >> 2;
    const int bn = (blockIdx.x & 3) * 64;
    const int tid = threadIdx.x, lane = tid & 63, w = tid >> 6;
    const int bm = blockIdx.y * 128;
    const int rloc = w * 16 + (lane >> 2);
    const int swz_src = ((lane & 3) ^ ((lane >> 3) & 3)) * 16;
    const int sread = ((lane >> 4) ^ ((lane >> 1) & 3)) * 16;

    const unsigned short *A1h, *A1l, *A2h, *A2l, *Wh, *Wl;
    const float* bias;
    int Ktot;
    size_t strA2, strB;
    if (half == 0) {
        A1h = xsh; A1l = xsl; A2h = l1h; A2l = l1l; strA2 = 1024;
        Wh = wost_h; Wl = wost_l; strB = 2048; Ktot = 1024; bias = b_out_self;
    } else {
        A1h = xnh; A1l = xnl; A2h = g2h; A2l = g2l; strA2 = 512;
        Wh = wot_h; Wl = wot_l; strB = 1536; Ktot = 768; bias = b_out;
    }
    const int nsteps = Ktot / 32;
    const char* Bh = (const char*)Wh + (size_t)bn * strB + swz_src;
    const char* Bl = (const char*)Wl + (size_t)bn * strB + swz_src;

    auto asrc = [&](int k0, const char*& sh, const char*& sl, size_t& st) {
        if (k0 < 512) {
            sh = (const char*)A1h + (size_t)bm * 1024 + (size_t)k0 * 2 + swz_src;
            sl = (const char*)A1l + (size_t)bm * 1024 + (size_t)k0 * 2 + swz_src;
            st = 1024;
        } else {
            sh = (const char*)A2h + (size_t)bm * strA2 + (size_t)(k0 - 512) * 2 + swz_src;
            sl = (const char*)A2l + (size_t)bm * strA2 + (size_t)(k0 - 512) * 2 + swz_src;
            st = strA2;
        }
    };

    f32x4 acc[2][4] = {};
    {
        const char *sh, *sl; size_t st;
        asrc(0, sh, sl, st);
        stage_g(smem, sh, sl, st, Bh, Bl, strB, rloc, w);
    }
    __syncthreads();
    for (int ks = 0; ks < nsteps; ++ks) {
        char* cur = smem + (ks & 1) * 24576;
        if (ks + 1 < nsteps) {
            const char *sh, *sl; size_t st;
            asrc((ks + 1) * 32, sh, sl, st);
            stage_g(smem + ((ks + 1) & 1) * 24576, sh, sl, st,
                    Bh + (size_t)(ks + 1) * 64, Bl + (size_t)(ks + 1) * 64, strB, rloc, w);
        }
        core_2x4(cur, w, sread, lane, acc);
        __syncthreads();
    }

    const int rj = (lane >> 4) * 4, cc = lane & 15;
    const int zoff = half * 256;
#pragma unroll
    for (int m = 0; m < 2; ++m) {
#pragma unroll
        for (int n = 0; n < 4; ++n) {
            const int col = bn + n * 16 + cc;  // 0..255 within half
            const float bv = bias[col];
#pragma unroll
            for (int j = 0; j < 4; ++j) {
                const int row = bm + w * 32 + m * 16 + rj + j;
                float x = acc[m][n][j] + bv;
                unsigned short h = f2bf_rn(x);
                zhi[(size_t)row * 512 + zoff + col] = h;
                zlo[(size_t)row * 512 + zoff + col] = f2bf_rn(x - bf2f(h));
            }
        }
    }
}

// ---------------- GCN aggregation, unroll-8 gathers ----------------
template <int MODE>
__global__ __launch_bounds__(256) void k_agg2(
    const int* __restrict__ row_start, const int* __restrict__ slist,
    const float* __restrict__ wlist, const float* __restrict__ dinv,
    const float* __restrict__ h,
    const float* __restrict__ bc, const float* __restrict__ b2,
    float* __restrict__ outf,
    unsigned short* __restrict__ oh, unsigned short* __restrict__ ol) {
    const int n = blockIdx.x;
    const int c = threadIdx.x;
    const float di = dinv[n];
    float acc = di * di * h[(size_t)n * 256 + c];
    float sv = di * di;
    const int e0 = row_start[n], e1 = row_start[n + 1];
    int j = e0;
    for (; j + 8 <= e1; j += 8) {
        int ss[8];
        float ww[8], vv[8];
#pragma unroll
        for (int u = 0; u < 8; ++u) { ss[u] = slist[j + u]; ww[u] = wlist[j + u]; }
#pragma unroll
        for (int u = 0; u < 8; ++u) vv[u] = h[(size_t)ss[u] * 256 + c];
#pragma unroll
        for (int u = 0; u < 8; ++u) {
            acc += ww[u] * vv[u];
            if (MODE) sv += ww[u];
        }
    }
    for (; j < e1; ++j) {
        const float wv = wlist[j];
        acc += wv * h[(size_t)slist[j] * 256 + c];
        if (MODE) sv += wv;
    }
    if (MODE == 0) {
        outf[(size_t)n * 256 + c] = acc;
    } else {
        float x = acc + sv * bc[c] + b2[c];
        unsigned short hb = f2bf_rn(x);
        oh[(size_t)n * 256 + c] = hb;
        ol[(size_t)n * 256 + c] = f2bf_rn(x - bf2f(hb));
    }
}

// ---------------- out = sigmoid(Z Z^T), 2-phase dbuf + NT stores ----------------
__device__ __forceinline__ void zzt_stage(char* buf, const char* s0, const char* s1,
                                          const char* s2, const char* s3,
                                          int rloc, int swz_src, int w, int kbyte) {
    const char* srcs[4] = {s0, s1, s2, s3};
#pragma unroll
    for (int tile = 0; tile < 4; ++tile) {
#pragma unroll
        for (int i = 0; i < 2; ++i) {
            const char* gp = srcs[tile] + (size_t)(rloc + i * 64) * 1024 + kbyte + swz_src;
            char* lp = buf + tile * 8192 + i * 4096 + w * 1024;
            gload16(gp, lp);
        }
    }
}

__global__ __launch_bounds__(256) void k_zzt_mfma(const unsigned short* __restrict__ zhi,
                                                  const unsigned short* __restrict__ zlo,
                                                  float* __restrict__ out) {
    __shared__ __align__(16) char smem[65536];  // 2 x 32KB
    const int tid = threadIdx.x;
    const int lane = tid & 63;
    const int w = tid >> 6;
    const int wr = w >> 1, wc = w & 1;

    const int t = blockIdx.x;
    int bi = (int)((sqrtf(8.0f * (float)t + 1.0f) - 1.0f) * 0.5f);
    while ((bi + 1) * (bi + 2) / 2 <= t) ++bi;
    while (bi * (bi + 1) / 2 > t) --bi;
    const int bj = t - bi * (bi + 1) / 2;

    const char* s0 = (const char*)zhi + (size_t)(bi * 128) * 1024;
    const char* s1 = (const char*)zlo + (size_t)(bi * 128) * 1024;
    const char* s2 = (const char*)zhi + (size_t)(bj * 128) * 1024;
    const char* s3 = (const char*)zlo + (size_t)(bj * 128) * 1024;

    const int rloc = w * 16 + (lane >> 2);
    const int swz_src = ((lane & 3) ^ ((lane >> 3) & 3)) * 16;
    const int sread = ((lane >> 4) ^ ((lane >> 1) & 3)) * 16;

    f32x4 acc[4][4] = {};

    zzt_stage(smem, s0, s1, s2, s3, rloc, swz_src, w, 0);
    __syncthreads();

    for (int ks = 0; ks < 16; ++ks) {
        char* cur = smem + (ks & 1) * 32768;
        if (ks < 15)
            zzt_stage(smem + ((ks + 1) & 1) * 32768, s0, s1, s2, s3, rloc, swz_src, w,
                      (ks + 1) * 64);

        bf16x8 ah[4], al[4], bh[4], bl[4];
        const char* pa = cur + (wr * 64 + (lane & 15)) * 64 + sread;
        const char* pb = cur + 16384 + (wc * 64 + (lane & 15)) * 64 + sread;
#pragma unroll
        for (int m = 0; m < 4; ++m) {
            ah[m] = *(const bf16x8*)(pa + m * 1024);
            al[m] = *(const bf16x8*)(pa + 8192 + m * 1024);
        }
#pragma unroll
        for (int n = 0; n < 4; ++n) {
            bh[n] = *(const bf16x8*)(pb + n * 1024);
            bl[n] = *(const bf16x8*)(pb + 8192 + n * 1024);
        }
#pragma unroll
        for (int m = 0; m < 4; ++m)
#pragma unroll
            for (int n = 0; n < 4; ++n) {
                acc[m][n] = __builtin_amdgcn_mfma_f32_16x16x32_bf16(ah[m], bh[n], acc[m][n], 0, 0, 0);
                acc[m][n] = __builtin_amdgcn_mfma_f32_16x16x32_bf16(ah[m], bl[n], acc[m][n], 0, 0, 0);
                acc[m][n] = __builtin_amdgcn_mfma_f32_16x16x32_bf16(al[m], bh[n], acc[m][n], 0, 0, 0);
            }
        __syncthreads();
    }

    const int rj = (lane >> 4) * 4;
    const int cc = lane & 15;
#pragma unroll
    for (int m = 0; m < 4; ++m) {
#pragma unroll
        for (int n = 0; n < 4; ++n) {
            float s[4];
#pragma unroll
            for (int j = 0; j < 4; ++j)
                s[j] = 1.0f / (1.0f + __expf(-acc[m][n][j]));
            const int gr0 = bi * 128 + wr * 64 + m * 16 + rj;
            const int gc  = bj * 128 + wc * 64 + n * 16 + cc;
#pragma unroll
            for (int j = 0; j < 4; ++j)
                __builtin_nontemporal_store(s[j], out + (size_t)(gr0 + j) * NNODE + gc);
            if (bi != bj) {
                const int mr = bj * 128 + wc * 64 + n * 16 + cc;
                const int mc = bi * 128 + wr * 64 + m * 16 + rj;
                f32x4 v = {s[0], s[1], s[2], s[3]};
                __builtin_nontemporal_store(v, (f32x4*)(out + (size_t)mr * NNODE + mc));
            }
        }
    }
}

// ---------------- launch ----------------
extern "C" void kernel_launch(void* const* d_in, const int* in_sizes, int n_in,
                              void* d_out, int out_size, void* d_ws, size_t ws_size,
                              hipStream_t stream) {
    const float* x_self     = (const float*)d_in[0];
    const float* x_neighbor = (const float*)d_in[1];
    const int*   ei         = (const int*)d_in[2];
    const float* w_in_self  = (const float*)d_in[3];
    const float* b_in_self  = (const float*)d_in[4];
    const float* w_out_self = (const float*)d_in[5];
    const float* b_out_self = (const float*)d_in[6];
    const float* gw1        = (const float*)d_in[7];
    const float* gb1        = (const float*)d_in[8];
    const float* gw2        = (const float*)d_in[9];
    const float* gb2        = (const float*)d_in[10];
    const float* w_out      = (const float*)d_in[11];
    const float* b_out      = (const float*)d_in[12];
    float* out = (float*)d_out;

    char* ws = (char*)d_ws;
    const size_t MB = 1024 * 1024;
    const size_t KB = 1024;
    int*   cnt       = (int*)(ws + 0);
    int*   row_start = (int*)(ws + 32 * KB);
    int*   cursor    = (int*)(ws + 96 * KB);
    float* dinv      = (float*)(ws + 128 * KB);
    float* bc        = (float*)(ws + 192 * KB);
    int*   slist     = (int*)(ws + 2 * MB);
    float* wlist     = (float*)(ws + 3 * MB);
    unsigned short* xsh = (unsigned short*)(ws + 4 * MB);
    unsigned short* xsl = (unsigned short*)(ws + 12 * MB);
    unsigned short* xnh = (unsigned short*)(ws + 20 * MB);
    unsigned short* xnl = (unsigned short*)(ws + 28 * MB);
    unsigned short* l1h = (unsigned short*)(ws + 36 * MB);
    unsigned short* l1l = (unsigned short*)(ws + 44 * MB);
    float*          hc  = (float*)(ws + 52 * MB);   // 8 MB fp32 [8192,256]
    float*          t1  = (float*)(ws + 60 * MB);   // 8 MB fp32
    unsigned short* g2h = (unsigned short*)(ws + 68 * MB);
    unsigned short* g2l = (unsigned short*)(ws + 72 * MB);
    unsigned short* zhi = (unsigned short*)(ws + 76 * MB);
    unsigned short* zlo = (unsigned short*)(ws + 84 * MB);
    unsigned short* wAt_h = (unsigned short*)(ws + 92 * MB);   // [768,512]
    unsigned short* wAt_l = (unsigned short*)(ws + 93 * MB);
    unsigned short* wost_h = (unsigned short*)(ws + 94 * MB);  // [256,1024]
    unsigned short* wost_l = (unsigned short*)(ws + 95 * MB);
    unsigned short* wot_h  = (unsigned short*)(ws + 96 * MB);  // [256,768]
    unsigned short* wot_l  = (unsigned short*)(ws + 97 * MB);

    const int* srcA = ei;          // edge_index[0]
    const int* dstA = ei + NEDGE;  // edge_index[1]

    // prep (splits + all weight transforms), independent of CSR
    k_prep<<<9025, 256, 0, stream>>>(x_self, x_neighbor, w_in_self, w_out_self, w_out,
                                     gw1, gw2, gb1, xsh, xsl, xnh, xnl,
                                     wAt_h, wAt_l, wost_h, wost_l, wot_h, wot_l, bc);

    // CSR build
    k_zero_int<<<NNODE / 256, 256, 0, stream>>>(cnt, NNODE);
    k_count<<<NEDGE / 256, 256, 0, stream>>>(dstA, cnt, NEDGE);
    k_scan<<<1, 256, 0, stream>>>(cnt, row_start, cursor, dinv);
    k_fill_csr2<<<NEDGE / 256, 256, 0, stream>>>(srcA, dstA, cursor, dinv, slist, wlist, NEDGE);

    // fused GEMM: xs @ [Win | Wc] -> l1 (relu, split) + hc (fp32)
    k_gemm128_A<<<dim3(12, NNODE / 128), 256, 0, stream>>>(
        xsh, xsl, wAt_h, wAt_l, b_in_self, l1h, l1l, hc);

    // double aggregation: t1 = S hc ; g2 = S t1 + svec*bc + gb2 (split, svec inline)
    k_agg2<0><<<NNODE, 256, 0, stream>>>(row_start, slist, wlist, dinv, hc,
                                         nullptr, nullptr, t1, nullptr, nullptr);
    k_agg2<1><<<NNODE, 256, 0, stream>>>(row_start, slist, wlist, dinv, t1,
                                         bc, gb2, nullptr, g2h, g2l);

    // z = [ [xs|l1]@wost + b_os , [xn|g2]@wot + b_o ]  (split into zhi/zlo)
    k_gemm128_Z<<<dim3(8, NNODE / 128), 256, 0, stream>>>(
        xsh, xsl, l1h, l1l, xnh, xnl, g2h, g2l,
        wost_h, wost_l, wot_h, wot_l, b_out_self, b_out, zhi, zlo);

    // out = sigmoid(z z^T)
    k_zzt_mfma<<<64 * 65 / 2, 256, 0, stream>>>(zhi, zlo, out);
}